// Round 5
// baseline (1700.484 us; speedup 1.0000x reference)
//
#include <hip/hip_runtime.h>

typedef unsigned short u16;
typedef unsigned int   u32;
typedef short s16x8 __attribute__((ext_vector_type(8)));   // 8 bf16 lanes for MFMA
typedef float f32x4 __attribute__((ext_vector_type(4)));

// ---- bf16 helpers (store with round-to-nearest-even) ----
static __device__ __forceinline__ float bf2f(u16 v){ return __uint_as_float(((u32)v)<<16); }
static __device__ __forceinline__ u16 f2bf(float f){
  u32 u = __float_as_uint(f);
  u32 r = (u + 0x7fffu + ((u>>16)&1u)) >> 16;
  return (u16)r;
}
static __device__ __forceinline__ float cvt(float v){ return v; }
static __device__ __forceinline__ float cvt(u16 v){ return bf2f(v); }
static __device__ __forceinline__ void stv(float* p, float v){ *p = v; }
static __device__ __forceinline__ void stv(u16* p, float v){ *p = f2bf(v); }

static __device__ __forceinline__ void ld2(const float* p, float& a, float& b){
  float2 t = *(const float2*)p; a=t.x; b=t.y;
}
static __device__ __forceinline__ void ld2(const u16* p, float& a, float& b){
  u32 t = *(const u32*)p; a = __uint_as_float(t<<16); b = __uint_as_float(t & 0xffff0000u);
}
static __device__ __forceinline__ void st2(float* p, float a, float b){
  float2 t; t.x=a; t.y=b; *(float2*)p = t;
}
static __device__ __forceinline__ void st2(u16* p, float a, float b){
  *(u32*)p = ((u32)f2bf(a)) | (((u32)f2bf(b))<<16);
}

// ---------------- RMSNorm: O = X / rms(X) * scale, vectorized 2-wide ----------------
template<typename TI, typename TO>
__global__ __launch_bounds__(256) void rms_k(const TI* __restrict__ X,
                                             const float* __restrict__ scale,
                                             TO* __restrict__ O)
{
  int row = blockIdx.x*4 + (threadIdx.x>>6);
  int lane = threadIdx.x&63;
  const TI* xr = X + (size_t)row*384;
  float v[6]; float ss = 0.f;
#pragma unroll
  for(int i=0;i<3;i++){
    ld2(xr + 2*lane + 128*i, v[2*i], v[2*i+1]);
    ss += v[2*i]*v[2*i] + v[2*i+1]*v[2*i+1];
  }
#pragma unroll
  for(int off=32; off>0; off>>=1) ss += __shfl_down(ss, off, 64);
  ss = __shfl(ss, 0, 64);
  float r = rsqrtf(ss*(1.0f/384.0f)+1e-6f);
  TO* orow = O + (size_t)row*384;
#pragma unroll
  for(int i=0;i<3;i++){
    int c = 2*lane + 128*i;
    st2(orow + c, v[2*i]*r*scale[c], v[2*i+1]*r*scale[c+1]);
  }
}

// ---------------- transpose + cast fp32 -> bf16: Out[c][r] = (r<Rr ? In[r][c] : 0) ----------------
__global__ __launch_bounds__(256) void tcast_k(const float* __restrict__ In, long isz,
                                               u16* __restrict__ Out, long osz,
                                               int Rr, int Cc, int ldo)
{
  __shared__ float t[32][33];
  const int z = blockIdx.z;
  const float* I = In + (long)z*isz;
  u16* Oz = Out + (long)z*osz;
  const int r0 = blockIdx.x*32, c0 = blockIdx.y*32;
  const int tx = threadIdx.x&31, ty = threadIdx.x>>5;
#pragma unroll
  for(int rr=ty; rr<32; rr+=8){
    int r = r0+rr, c = c0+tx;
    t[rr][tx] = (r<Rr && c<Cc) ? I[(size_t)r*Cc + c] : 0.f;
  }
  __syncthreads();
#pragma unroll
  for(int cc=ty; cc<32; cc+=8){
    int c = c0+cc, r = r0+tx;
    if(c<Cc && r<ldo) Oz[(size_t)c*ldo + r] = f2bf(t[tx][cc]);
  }
}

// ============ full-N bf16 MFMA GEMM: C[m, 0..BN) = A[M,K] @ Bt[N,K]^T ============
// BM=128, BN=NF*32 (whole N in one block -> A fetched exactly once).
// 4 waves (2m x 2n), acc 4xNF f32x4. Single-buffer LDS, K-step 32.
// Output addr = (m>>8)*cs_hi + (m&255)*cs_lo + (n>>6)*csz + (n&63)
//   csz=64: identity (row-major, ld = cs_lo); csz=16384: QKV [b][h,j][t][64] scatter.
// XCD-chunked mapping: same-m n-blocks consecutive on one XCD (L2 reuse for nby>1).
template<int NF, typename TC, typename TR>
__global__ __launch_bounds__(256,2) void mgemmN_k(
    const u16* __restrict__ A, int lda,
    const u16* __restrict__ Bt, int ldb,
    TC* __restrict__ C, long cs_hi, int cs_lo, int csz,
    const TR* __restrict__ R,
    const float* __restrict__ bias,
    int N, int Nstore, int K, float beta, int relu, int nby)
{
  constexpr int BN = NF*32;
  __shared__ __align__(16) u16 As[128*40];
  __shared__ __align__(16) u16 Bs[BN*40];
  const int d = blockIdx.x;
  const int xcd = d&7, slot = d>>3;
  const int bm = xcd*64 + slot/nby;
  const int bn = slot - (slot/nby)*nby;
  const int m0 = bm*128, n0 = bn*BN;
  const int tid = threadIdx.x;
  const int w = tid>>6, lane = tid&63;
  const int g4 = lane>>4, l16 = lane&15;
  const int wr = w>>1, wc = w&1;
  const int arow = tid>>1, akc = (tid&1)*16;

  f32x4 fz = {0.f,0.f,0.f,0.f};
  f32x4 acc[4][NF];
#pragma unroll
  for(int i=0;i<4;i++)
#pragma unroll
    for(int j=0;j<NF;j++) acc[i][j]=fz;

  for(int k0=0;k0<K;k0+=32){
    {
      const u16* ga = &A[(size_t)(m0+arow)*lda + k0 + akc];
      uint4 a0 = *(const uint4*)ga;
      uint4 a1 = *(const uint4*)(ga+8);
      *(uint4*)&As[arow*40 + akc]     = a0;
      *(uint4*)&As[arow*40 + akc + 8] = a1;
    }
#pragma unroll
    for(int j=0;j<(BN+127)/128;j++){
      int brow = (tid>>1) + 128*j;
      if(brow < BN){
        int gn = n0 + brow;
        uint4 b0 = make_uint4(0,0,0,0), b1 = b0;
        if(gn < N){
          const u16* gb = &Bt[(size_t)gn*ldb + k0 + akc];
          b0 = *(const uint4*)gb;
          b1 = *(const uint4*)(gb+8);
        }
        *(uint4*)&Bs[brow*40 + akc]     = b0;
        *(uint4*)&Bs[brow*40 + akc + 8] = b1;
      }
    }
    __syncthreads();
    s16x8 av[4];
#pragma unroll
    for(int mf=0;mf<4;mf++)
      av[mf] = *(const s16x8*)&As[(wr*64 + mf*16 + l16)*40 + g4*8];
#pragma unroll
    for(int nf=0;nf<NF;nf++){
      s16x8 bv = *(const s16x8*)&Bs[(wc*(NF*16) + nf*16 + l16)*40 + g4*8];
#pragma unroll
      for(int mf=0;mf<4;mf++)
        acc[mf][nf] = __builtin_amdgcn_mfma_f32_16x16x32_bf16(av[mf], bv, acc[mf][nf], 0,0,0);
    }
    __syncthreads();
  }
  // epilogue: D layout col=lane&15, row=(lane>>4)*4+i
#pragma unroll
  for(int mf=0;mf<4;mf++)
#pragma unroll
    for(int i=0;i<4;i++){
      int m = m0 + wr*64 + mf*16 + g4*4 + i;
      long rowoff = (long)(m>>8)*cs_hi + (long)(m&255)*cs_lo;
#pragma unroll
      for(int nf=0;nf<NF;nf++){
        int gn = n0 + wc*(NF*16) + nf*16 + l16;
        if(gn < Nstore){
          long addr = rowoff + (long)(gn>>6)*csz + (gn&63);
          float v = 0.f;
          if(gn < N){
            v = acc[mf][nf][i];
            if(R)    v += beta*cvt(R[addr]);
            if(bias) v += bias[gn];
            if(relu) v  = fmaxf(v, 0.f);
          }
          stv(C + addr, v);
        }
      }
    }
}

// ---------------- MFMA causal flash attention: one block per (b,h), T=256, HS=64 ----------------
// QKV packed [B,H,{q,k,v},T,64] bf16: Qb = QKV + bh*49152, K at +16384, V at +32768.
__global__ __launch_bounds__(256,2) void mattn_k(const u16* __restrict__ QKV,
                                                 u16* __restrict__ O)
{
  __shared__ __align__(16) u16 Ks[64*64];    // [s][d], byte = s*128+2d ^ ((s&7)<<4)
  __shared__ __align__(16) u16 Vts[64*64];   // [d][s], byte = d*128+2s ^ ((d&7)<<4)
  __shared__ __align__(16) u16 Ps[4*4096];   // per-wave [m][s], byte = m*128+2s ^ ((m&7)<<4)
  const int bh = blockIdx.x;
  const int b = bh/6, h = bh - b*6;
  const u16* Qb = QKV + (size_t)bh*49152;
  const u16* Kb = Qb + 16384;
  const u16* Vb = Qb + 32768;
  const int tid = threadIdx.x;
  const int w = tid>>6, lane = tid&63;
  const int g4 = lane>>4, l16 = lane&15;
  char* PB = (char*)&Ps[w*4096];
  const int swz = (l16&7)<<4;

  s16x8 qf[4][2];
#pragma unroll
  for(int mi=0;mi<4;mi++)
#pragma unroll
    for(int ks=0;ks<2;ks++)
      qf[mi][ks] = *(const s16x8*)(Qb + (size_t)(w*64 + mi*16 + l16)*64 + ks*32 + g4*8);

  f32x4 fzv = {0.f,0.f,0.f,0.f};
  f32x4 o[4][4];
#pragma unroll
  for(int mf=0;mf<4;mf++)
#pragma unroll
    for(int df=0;df<4;df++) o[mf][df]=fzv;
  float mrun[4], lrun[4];
#pragma unroll
  for(int mi=0;mi<4;mi++){ mrun[mi]=-1e30f; lrun[mi]=0.f; }

  for(int st=0; st<4; ++st){
    if(st) __syncthreads();
#pragma unroll
    for(int it=0; it<2; ++it){
      int c = tid + 256*it;
      int s = c>>3, d0 = (c&7)*8;
      uint4 ld = *(const uint4*)(Kb + (size_t)(st*64+s)*64 + d0);
      int byte = s*128 + d0*2; byte ^= (s&7)<<4;
      *(uint4*)((char*)Ks + byte) = ld;
    }
#pragma unroll
    for(int it=0; it<2; ++it){
      int c = tid + 256*it;
      int s = c&63, d0 = (c>>6)*8;
      uint4 ld = *(const uint4*)(Vb + (size_t)(st*64+s)*64 + d0);
#pragma unroll
      for(int jj=0; jj<4; ++jj){
        u32 ww = (jj==0)?ld.x:(jj==1)?ld.y:(jj==2)?ld.z:ld.w;
        int d = d0 + 2*jj;
        int byte0 = d*128 + s*2;     byte0 ^= (d&7)<<4;
        int byte1 = (d+1)*128 + s*2; byte1 ^= ((d+1)&7)<<4;
        *(u16*)((char*)Vts + byte0) = (u16)(ww & 0xffffu);
        *(u16*)((char*)Vts + byte1) = (u16)(ww >> 16);
      }
    }
    __syncthreads();
    if(w < st) continue;

    f32x4 sc[4][4];
#pragma unroll
    for(int sf=0; sf<4; ++sf){
      int row = sf*16 + l16;
      s16x8 kf0 = *(const s16x8*)((char*)Ks + ((row*128 + g4*16) ^ swz));
      s16x8 kf1 = *(const s16x8*)((char*)Ks + ((row*128 + 64 + g4*16) ^ swz));
#pragma unroll
      for(int mi=0; mi<4; ++mi){
        f32x4 t = __builtin_amdgcn_mfma_f32_16x16x32_bf16(kf0, qf[mi][0], fzv, 0,0,0);
        sc[sf][mi] = __builtin_amdgcn_mfma_f32_16x16x32_bf16(kf1, qf[mi][1], t, 0,0,0);
      }
    }
    float alpha[4];
#pragma unroll
    for(int mi=0; mi<4; ++mi){
      int mloc = mi*16 + l16;
      float rmax = -3.0e38f;
#pragma unroll
      for(int sf=0; sf<4; ++sf)
#pragma unroll
        for(int i=0;i<4;i++){
          float vv = sc[sf][mi][i]*0.125f;
          if(st==w && (sf*16 + g4*4 + i) > mloc) vv = -1e30f;
          sc[sf][mi][i] = vv;
          rmax = fmaxf(rmax, vv);
        }
      rmax = fmaxf(rmax, __shfl_xor(rmax, 16, 64));
      rmax = fmaxf(rmax, __shfl_xor(rmax, 32, 64));
      float mnew = fmaxf(mrun[mi], rmax);
      float al = __expf(mrun[mi] - mnew);
      mrun[mi] = mnew;
      float ls = 0.f;
#pragma unroll
      for(int sf=0; sf<4; ++sf){
        float p0 = __expf(sc[sf][mi][0]-mnew);
        float p1 = __expf(sc[sf][mi][1]-mnew);
        float p2 = __expf(sc[sf][mi][2]-mnew);
        float p3 = __expf(sc[sf][mi][3]-mnew);
        ls += p0+p1+p2+p3;
        ushort4 pk; pk.x=f2bf(p0); pk.y=f2bf(p1); pk.z=f2bf(p2); pk.w=f2bf(p3);
        int byte = mloc*128 + sf*32 + g4*8; byte ^= (l16&7)<<4;
        *(ushort4*)(PB + byte) = pk;
      }
      ls += __shfl_xor(ls, 16, 64);
      ls += __shfl_xor(ls, 32, 64);
      lrun[mi] = lrun[mi]*al + ls;
      alpha[mi] = al;
    }
#pragma unroll
    for(int mf=0; mf<4; ++mf)
#pragma unroll
      for(int i=0;i<4;i++){
        float at = __shfl(alpha[mf], g4*4 + i, 64);
#pragma unroll
        for(int df=0; df<4; ++df) o[mf][df][i] *= at;
      }
    s16x8 vbf[4][2];
#pragma unroll
    for(int df=0; df<4; ++df){
      int row = df*16 + l16;
      vbf[df][0] = *(const s16x8*)((char*)Vts + ((row*128 + g4*16) ^ swz));
      vbf[df][1] = *(const s16x8*)((char*)Vts + ((row*128 + 64 + g4*16) ^ swz));
    }
#pragma unroll
    for(int mf=0; mf<4; ++mf){
      int row = mf*16 + l16;
      s16x8 pa0 = *(const s16x8*)(PB + ((row*128 + g4*16) ^ swz));
      s16x8 pa1 = *(const s16x8*)(PB + ((row*128 + 64 + g4*16) ^ swz));
#pragma unroll
      for(int df=0; df<4; ++df){
        f32x4 t = __builtin_amdgcn_mfma_f32_16x16x32_bf16(pa0, vbf[df][0], o[mf][df], 0,0,0);
        o[mf][df] = __builtin_amdgcn_mfma_f32_16x16x32_bf16(pa1, vbf[df][1], t, 0,0,0);
      }
    }
  }
#pragma unroll
  for(int mf=0; mf<4; ++mf)
#pragma unroll
    for(int i=0;i<4;i++){
      float lt = __shfl(lrun[mf], g4*4 + i, 64);
      float rl = 1.f/lt;
      u16* orow = O + ((size_t)(b*256 + w*64 + mf*16 + g4*4 + i))*384 + h*64;
#pragma unroll
      for(int df=0; df<4; ++df)
        orow[df*16 + l16] = f2bf(o[mf][df][i]*rl);
    }
}

// ================= Newton-Schulz orthogonalization, stream-ordered =================
__global__ __launch_bounds__(256) void fpart_k(const float* __restrict__ W0,
                                               const float* __restrict__ W1,
                                               float* __restrict__ part)
{
  int b = blockIdx.x; int z = b/24, seg = b - z*24;
  const float* W = (z ? W1 : W0) + seg*6144;
  int tid = threadIdx.x;
  float s = 0.f;
  for(int i=tid;i<6144;i+=256){ float v=W[i]; s+=v*v; }
#pragma unroll
  for(int off=32; off>0; off>>=1) s += __shfl_down(s, off, 64);
  __shared__ float red[4];
  if((tid&63)==0) red[tid>>6]=s;
  __syncthreads();
  if(tid==0) part[b] = red[0]+red[1]+red[2]+red[3];
}

__global__ __launch_bounds__(64) void fcomb_k(const float* __restrict__ part,
                                              float* __restrict__ invb)
{
  int lane = threadIdx.x;
  float v = 0.f;
  if(lane < 24) v = part[lane];
  else if(lane >= 32 && lane < 56) v = part[lane - 8];
#pragma unroll
  for(int off=1; off<32; off<<=1) v += __shfl_xor(v, off, 64);
  if(lane==0)  invb[0] = rsqrtf(v);
  if(lane==32) invb[1] = rsqrtf(v);
}

__global__ __launch_bounds__(256) void nsinit_k(const float* __restrict__ W0,
                                                const float* __restrict__ W1,
                                                const float* __restrict__ invb,
                                                u16* __restrict__ XB)
{
  int b = blockIdx.x; int z = b/24, p = b - z*24, cp0 = p*16;
  const float* W = z ? W1 : W0;
  float inv = invb[z];
  u16* base = XB + (size_t)z*589824;
  u16* xh = base;            u16* xl = base + 147456;
  u16* th = base + 294912;   u16* tl = base + 442368;
  int tid = threadIdx.x;
  for(int idx=tid; idx<6144; idx+=256){
    int r = idx>>4, j = idx&15;
    float v = W[r*384 + cp0 + j]*inv;
    u16 hh = f2bf(v);
    xh[p*6144 + idx] = hh;
    xl[p*6144 + idx] = f2bf(v - bf2f(hh));
  }
  for(int idx=tid; idx<6144; idx+=256){
    int j = idx/384, r = idx - j*384;
    float v = W[(cp0+j)*384 + r]*inv;
    u16 hh = f2bf(v);
    th[p*6144 + r*16 + j] = hh;
    tl[p*6144 + r*16 + j] = f2bf(v - bf2f(hh));
  }
}

static __device__ __forceinline__ void ns_mm(
    const u16* __restrict__ Agh, const u16* __restrict__ Agl,
    u16* AhL, u16* AlL, const u16* BThL, const u16* BTlL,
    int tid, f32x4 acc[4])
{
  const int w = tid>>6, lane = tid&63, g4 = lane>>4, l16 = lane&15;
  const int o0 = (tid>>1)*24 + (tid&1)*8;
  const int o1 = o0 + 4608;
  const s16x8 z8 = {0,0,0,0,0,0,0,0};
  f32x4 fz = {0.f,0.f,0.f,0.f};
#pragma unroll
  for(int i=0;i<4;i++) acc[i]=fz;
  {
    uint4 h0 = *(const uint4*)(Agh + tid*8);
    uint4 h1 = *(const uint4*)(Agh + (384+tid)*8);
    uint4 l0 = *(const uint4*)(Agl + tid*8);
    uint4 l1 = *(const uint4*)(Agl + (384+tid)*8);
    *(uint4*)&AhL[o0] = h0; *(uint4*)&AhL[o1] = h1;
    *(uint4*)&AlL[o0] = l0; *(uint4*)&AlL[o1] = l1;
  }
  __syncthreads();
  for(int c=0;c<24;c++){
    uint4 nh0, nh1, nl0, nl1;
    if(c<23){
      const u16* ph = Agh + (c+1)*6144;
      const u16* pl = Agl + (c+1)*6144;
      nh0 = *(const uint4*)(ph + tid*8);
      nh1 = *(const uint4*)(ph + (384+tid)*8);
      nl0 = *(const uint4*)(pl + tid*8);
      nl1 = *(const uint4*)(pl + (384+tid)*8);
    }
    s16x8 bh = z8, bl = z8;
    if(g4<2){
      bh = *(const s16x8*)&BThL[l16*392 + c*16 + g4*8];
      bl = *(const s16x8*)&BTlL[l16*392 + c*16 + g4*8];
    }
#pragma unroll
    for(int tt=0;tt<4;tt++){
      int rb = 64*w + 16*tt + l16;
      s16x8 ah = z8, al = z8;
      if(g4<2){
        ah = *(const s16x8*)&AhL[rb*24 + g4*8];
        al = *(const s16x8*)&AlL[rb*24 + g4*8];
      }
      acc[tt] = __builtin_amdgcn_mfma_f32_16x16x32_bf16(ah, bh, acc[tt], 0,0,0);
      acc[tt] = __builtin_amdgcn_mfma_f32_16x16x32_bf16(ah, bl, acc[tt], 0,0,0);
      acc[tt] = __builtin_amdgcn_mfma_f32_16x16x32_bf16(al, bh, acc[tt], 0,0,0);
    }
    __syncthreads();
    if(c<23){
      *(uint4*)&AhL[o0] = nh0; *(uint4*)&AhL[o1] = nh1;
      *(uint4*)&AlL[o0] = nl0; *(uint4*)&AlL[o1] = nl1;
      __syncthreads();
    }
  }
}

__global__ __launch_bounds__(384) void nsit_k(u16* __restrict__ XB,
                                              u16* __restrict__ QT,
                                              int it, int niter, int nq)
{
  __shared__ __align__(16) u16 AhL[384*24];
  __shared__ __align__(16) u16 AlL[384*24];
  __shared__ __align__(16) u16 BTh[16*392];
  __shared__ __align__(16) u16 BTl[16*392];
  const int blk = blockIdx.x;
  const int z = blk/24, p = blk - z*24, cp0 = p*16;
  const int tid = threadIdx.x;
  const int w = tid>>6, lane = tid&63, g4 = lane>>4, l16 = lane&15;
  const int rs = it&1, ws2 = rs^1;
  const u16* bin  = XB + (size_t)rs*1179648  + (size_t)z*589824;
  u16*       bout = XB + (size_t)ws2*1179648 + (size_t)z*589824;
  const u16* Xh  = bin;            const u16* Xl  = bin + 147456;
  const u16* Th  = bin + 294912;   const u16* Tl  = bin + 442368;

  {
    const u16* sh = Xh + p*6144;
    const u16* sl = Xl + p*6144;
    for(int i=tid; i<768; i+=384){
      int k = i>>1, n0 = (i&1)*8;
      uint4 vh = *(const uint4*)(sh + i*8);
      uint4 vl = *(const uint4*)(sl + i*8);
#pragma unroll
      for(int j=0;j<8;j++){
        BTh[(n0+j)*392 + k] = ((u16*)&vh)[j];
        BTl[(n0+j)*392 + k] = ((u16*)&vl)[j];
      }
    }
  }
  __syncthreads();

  const bool quint = (it < nq);
  f32x4 acc[4], gsv[4];

  ns_mm(Th, Tl, AhL, AlL, BTh, BTl, tid, acc);
  if(quint){
#pragma unroll
    for(int tt=0;tt<4;tt++){
      gsv[tt] = acc[tt];
      int m0 = 64*w + 16*tt + g4*4;
      ushort4 h4, l4;
#pragma unroll
      for(int i=0;i<4;i++){
        float v = acc[tt][i];
        u16 hh = f2bf(v);
        ((u16*)&h4)[i]=hh; ((u16*)&l4)[i]=f2bf(v - bf2f(hh));
      }
      *(ushort4*)&BTh[l16*392 + m0] = h4;
      *(ushort4*)&BTl[l16*392 + m0] = l4;
    }
    __syncthreads();
    ns_mm(Xh, Xl, AhL, AlL, BTh, BTl, tid, acc);
#pragma unroll
    for(int tt=0;tt<4;tt++){
      int m0 = 64*w + 16*tt + g4*4;
      ushort4 h4, l4;
#pragma unroll
      for(int i=0;i<4;i++){
        float v = acc[tt][i];
        u16 hh = f2bf(v);
        ((u16*)&h4)[i]=hh; ((u16*)&l4)[i]=f2bf(v - bf2f(hh));
      }
      *(ushort4*)&BTh[l16*392 + m0] = h4;
      *(ushort4*)&BTl[l16*392 + m0] = l4;
    }
    __syncthreads();
    ns_mm(Th, Tl, AhL, AlL, BTh, BTl, tid, acc);
    __syncthreads();
#pragma unroll
    for(int tt=0;tt<4;tt++){
      int m0 = 64*w + 16*tt + g4*4;
      ushort4 gh = *(const ushort4*)&BTh[l16*392 + m0];
      ushort4 gl = *(const ushort4*)&BTl[l16*392 + m0];
      (void)gh; (void)gl;
      ushort4 h4, l4;
#pragma unroll
      for(int i=0;i<4;i++){
        float v = fmaf(2.0315f, acc[tt][i], -4.7750f*(gsv[tt][i]))
                + ((m0+i)==(cp0+l16) ? 3.4445f : 0.f);
        u16 hh = f2bf(v);
        ((u16*)&h4)[i]=hh; ((u16*)&l4)[i]=f2bf(v - bf2f(hh));
      }
      *(ushort4*)&BTh[l16*392 + m0] = h4;
      *(ushort4*)&BTl[l16*392 + m0] = l4;
    }
    __syncthreads();
  } else {
#pragma unroll
    for(int tt=0;tt<4;tt++){
      int m0 = 64*w + 16*tt + g4*4;
      ushort4 h4, l4;
#pragma unroll
      for(int i=0;i<4;i++){
        float v = -0.5f*acc[tt][i] + ((m0+i)==(cp0+l16) ? 1.5f : 0.f);
        u16 hh = f2bf(v);
        ((u16*)&h4)[i]=hh; ((u16*)&l4)[i]=f2bf(v - bf2f(hh));
      }
      *(ushort4*)&BTh[l16*392 + m0] = h4;
      *(ushort4*)&BTl[l16*392 + m0] = l4;
    }
    __syncthreads();
  }
  ns_mm(Xh, Xl, AhL, AlL, BTh, BTl, tid, acc);

  if(it == niter-1){
    u16* q = QT + (size_t)z*147456 + (size_t)(cp0+l16)*384;
#pragma unroll
    for(int tt=0;tt<4;tt++){
      int m0 = 64*w + 16*tt + g4*4;
      ushort4 h4;
#pragma unroll
      for(int i=0;i<4;i++) ((u16*)&h4)[i] = f2bf(acc[tt][i]);
      *(ushort4*)&q[m0] = h4;
    }
  } else {
    u16* oXh = bout + p*6144;            u16* oXl = bout + 147456 + p*6144;
    u16* oTh = bout + 294912;            u16* oTl = bout + 442368;
#pragma unroll
    for(int tt=0;tt<4;tt++){
      int m0 = 64*w + 16*tt + g4*4;
      ushort4 h4, l4;
#pragma unroll
      for(int i=0;i<4;i++){
        float v = acc[tt][i];
        u16 hh = f2bf(v);
        ((u16*)&h4)[i]=hh; ((u16*)&l4)[i]=f2bf(v - bf2f(hh));
        oXh[(m0+i)*16 + l16] = hh;
        oXl[(m0+i)*16 + l16] = ((u16*)&l4)[i];
      }
      size_t to = (size_t)(4*w+tt)*6144 + (size_t)(cp0+l16)*16 + g4*4;
      *(ushort4*)&oTh[to] = h4;
      *(ushort4*)&oTl[to] = l4;
    }
  }
}

// ---------------- host-side orchestration ----------------
extern "C" void kernel_launch(void* const* d_in, const int* in_sizes, int n_in,
                              void* d_out, int out_size, void* d_ws, size_t ws_size,
                              hipStream_t stream)
{
  const float* x      = (const float*)d_in[0];
  const float* Wq     = (const float*)d_in[1];
  const float* Wk     = (const float*)d_in[2];
  const float* Wv     = (const float*)d_in[3];
  const float* Wp     = (const float*)d_in[4];
  const float* bp     = (const float*)d_in[5];
  const float* scale1 = (const float*)d_in[6];
  const float* scale2 = (const float*)d_in[7];
  const float* W1     = (const float*)d_in[8];
  const float* b1     = (const float*)d_in[9];
  const float* W2     = (const float*)d_in[10];
  const float* b2     = (const float*)d_in[11];
  const float* Wo_in  = (const float*)d_in[12];
  const float* Wo_out = (const float*)d_in[13];

  // ---- workspace layout ----
  char* ws = (char*)d_ws;
  u16* XB   = (u16*)(ws + 0);                 // NS X buffers (4.7 MB)
  u16* Wqkv = (u16*)(ws + 4719104L);          // [h][{q,k,v}][64][384] bf16
  u16* WpT  = (u16*)(ws + 5603840L);          // [384][384]
  u16* W1T  = (u16*)(ws + 5898752L);          // [307][384]
  u16* W2T  = (u16*)(ws + 6134528L);          // [384][320] (k-padded with zeros)
  u16* QT   = (u16*)(ws + 6380288L);          // orth(Wo_in)^T, orth(Wo_out)^T bf16
  float* part = (float*)(ws + 6970112L);      // 48 floats
  float* invb = (float*)(ws + 6970496L);      // 2 floats
  u16* h1b  = (u16*)(ws + 8388608L);          // S0: h1 -> h6                (48 MB)
  u16* qkvb = (u16*)(ws + 58720256L);         // S1-S3: qkv packed -> h2/h3/h4 (144 MB)
  u16* atb  = (u16*)(ws + 209715200L);        // S4: attn_cat [65536][384] -> h5 [65536][320]
  u16* h2b = qkvb;
  u16* h3b = qkvb + 25165824L;
  u16* h4b = qkvb + 50331648L;
  u16* h5b = atb;
  u16* h6b = h1b;

  // --- weight transpose+cast ---
  tcast_k<<<dim3(12, 2,6),256,0,stream>>>(Wq,24576L, Wqkv,        73728L, 384, 64,384);
  tcast_k<<<dim3(12, 2,6),256,0,stream>>>(Wk,24576L, Wqkv+24576L, 73728L, 384, 64,384);
  tcast_k<<<dim3(12, 2,6),256,0,stream>>>(Wv,24576L, Wqkv+49152L, 73728L, 384, 64,384);
  tcast_k<<<dim3(12,12,1),256,0,stream>>>(Wp,0L,     WpT,0L,     384,384,384);
  tcast_k<<<dim3(12,10,1),256,0,stream>>>(W1,0L,     W1T,0L,     384,307,384);
  tcast_k<<<dim3(10,12,1),256,0,stream>>>(W2,0L,     W2T,0L,     307,384,320);

  // --- orth via stream-ordered Newton-Schulz chain (10 quintic + 5 cubic) ---
  const int NITER = 15, NQ = 10;
  fpart_k<<<48,256,0,stream>>>(Wo_in, Wo_out, part);
  fcomb_k<<<1,64,0,stream>>>(part, invb);
  nsinit_k<<<48,256,0,stream>>>(Wo_in, Wo_out, invb, XB);
  for(int it=0; it<NITER; ++it)
    nsit_k<<<48,384,0,stream>>>(XB, QT, it, NITER, NQ);

  // --- main path: bf16 activations + MFMA, full-N blocks (A fetched once) ---
  rms_k<float,u16><<<16384,256,0,stream>>>(x, scale1, h1b);
  // QKV: N=1152 in 3 n-tiles, XCD-co-located; scatter to [b][h,j][t][64]
  mgemmN_k<12,u16,float><<<1536,256,0,stream>>>(
      h1b,384,  Wqkv,384,
      qkvb, 294912L,64,16384,
      (const float*)nullptr, nullptr,
      1152,1152,384, 0.f,0, 3);
  mattn_k<<<1536,256,0,stream>>>(qkvb, atb);
  // h2 = attn@Wp + bp + h1
  mgemmN_k<12,u16,u16><<<512,256,0,stream>>>(
      atb,384,  WpT,384,
      h2b, 98304L,384,64,
      h1b, bp,
      384,384,384, 1.f,0, 1);
  rms_k<u16,u16><<<16384,256,0,stream>>>(h2b, scale2, h3b);
  // h4 = h3 @ orth(Wo_in)
  mgemmN_k<12,u16,float><<<512,256,0,stream>>>(
      h3b,384,  QT,384,
      h4b, 98304L,384,64,
      (const float*)nullptr, nullptr,
      384,384,384, 0.f,0, 1);
  // h5 = relu(h4@W1 + b1), N=307 stored ld 320, cols 307..319 zeroed
  mgemmN_k<10,u16,float><<<512,256,0,stream>>>(
      h4b,384,  W1T,384,
      h5b, 81920L,320,64,
      (const float*)nullptr, b1,
      307,320,384, 0.f,1, 1);
  // h6 = h5@W2 + b2  (K padded to 320)
  mgemmN_k<12,u16,float><<<512,256,0,stream>>>(
      h5b,320,  W2T,320,
      h6b, 98304L,384,64,
      (const float*)nullptr, b2,
      384,384,320, 0.f,0, 1);
  // out = h6 @ orth(Wo_out) + h6 -> fp32 d_out
  mgemmN_k<12,float,u16><<<512,256,0,stream>>>(
      h6b,384,  QT+147456,384,
      (float*)d_out, 98304L,384,64,
      h6b, nullptr,
      384,384,384, 1.f,0, 1);

  (void)in_sizes; (void)n_in; (void)ws_size; (void)out_size;
}

// Round 6
// 1595.045 us; speedup vs baseline: 1.0661x; 1.0661x over previous
//
#include <hip/hip_runtime.h>

typedef unsigned short u16;
typedef unsigned int   u32;
typedef short s16x8 __attribute__((ext_vector_type(8)));   // 8 bf16 lanes for MFMA
typedef float f32x4 __attribute__((ext_vector_type(4)));

// ---- bf16 helpers (store with round-to-nearest-even) ----
static __device__ __forceinline__ float bf2f(u16 v){ return __uint_as_float(((u32)v)<<16); }
static __device__ __forceinline__ u16 f2bf(float f){
  u32 u = __float_as_uint(f);
  u32 r = (u + 0x7fffu + ((u>>16)&1u)) >> 16;
  return (u16)r;
}
static __device__ __forceinline__ float cvt(float v){ return v; }
static __device__ __forceinline__ float cvt(u16 v){ return bf2f(v); }
static __device__ __forceinline__ void stv(float* p, float v){ *p = v; }
static __device__ __forceinline__ void stv(u16* p, float v){ *p = f2bf(v); }

static __device__ __forceinline__ void ld2(const float* p, float& a, float& b){
  float2 t = *(const float2*)p; a=t.x; b=t.y;
}
static __device__ __forceinline__ void ld2(const u16* p, float& a, float& b){
  u32 t = *(const u32*)p; a = __uint_as_float(t<<16); b = __uint_as_float(t & 0xffff0000u);
}
static __device__ __forceinline__ void st2(float* p, float a, float b){
  float2 t; t.x=a; t.y=b; *(float2*)p = t;
}
static __device__ __forceinline__ void st2(u16* p, float a, float b){
  *(u32*)p = ((u32)f2bf(a)) | (((u32)f2bf(b))<<16);
}

// async global->LDS, 16B per lane, dest = wave-uniform base + lane*16
static __device__ __forceinline__ void gload16(const u16* g, u16* l){
  __builtin_amdgcn_global_load_lds(
      (const __attribute__((address_space(1))) u32*)(const void*)g,
      (__attribute__((address_space(3))) u32*)(void*)l, 16, 0, 0);
}

// ---------------- RMSNorm: O = X / rms(X) * scale, vectorized 2-wide ----------------
template<typename TI, typename TO>
__global__ __launch_bounds__(256) void rms_k(const TI* __restrict__ X,
                                             const float* __restrict__ scale,
                                             TO* __restrict__ O)
{
  int row = blockIdx.x*4 + (threadIdx.x>>6);
  int lane = threadIdx.x&63;
  const TI* xr = X + (size_t)row*384;
  float v[6]; float ss = 0.f;
#pragma unroll
  for(int i=0;i<3;i++){
    ld2(xr + 2*lane + 128*i, v[2*i], v[2*i+1]);
    ss += v[2*i]*v[2*i] + v[2*i+1]*v[2*i+1];
  }
#pragma unroll
  for(int off=32; off>0; off>>=1) ss += __shfl_down(ss, off, 64);
  ss = __shfl(ss, 0, 64);
  float r = rsqrtf(ss*(1.0f/384.0f)+1e-6f);
  TO* orow = O + (size_t)row*384;
#pragma unroll
  for(int i=0;i<3;i++){
    int c = 2*lane + 128*i;
    st2(orow + c, v[2*i]*r*scale[c], v[2*i+1]*r*scale[c+1]);
  }
}

// ---------------- transpose + cast fp32 -> bf16: Out[c][r] = (r<Rr ? In[r][c] : 0) ----------------
__global__ __launch_bounds__(256) void tcast_k(const float* __restrict__ In, long isz,
                                               u16* __restrict__ Out, long osz,
                                               int Rr, int Cc, int ldo)
{
  __shared__ float t[32][33];
  const int z = blockIdx.z;
  const float* I = In + (long)z*isz;
  u16* Oz = Out + (long)z*osz;
  const int r0 = blockIdx.x*32, c0 = blockIdx.y*32;
  const int tx = threadIdx.x&31, ty = threadIdx.x>>5;
#pragma unroll
  for(int rr=ty; rr<32; rr+=8){
    int r = r0+rr, c = c0+tx;
    t[rr][tx] = (r<Rr && c<Cc) ? I[(size_t)r*Cc + c] : 0.f;
  }
  __syncthreads();
#pragma unroll
  for(int cc=ty; cc<32; cc+=8){
    int c = c0+cc, r = r0+tx;
    if(c<Cc && r<ldo) Oz[(size_t)c*ldo + r] = f2bf(t[tx][cc]);
  }
}

// ============ bf16 MFMA GEMM, BM=128 x BN=NF*32, BK=64, global_load_lds staging ============
// 4 waves 2x2: per-wave 64 x NF*16, acc[4][NF] (NF=6 -> 96 VGPR, no spill at lb(256,3)).
// LDS rows = 64 u16 (128 B), XOR-swizzled: u16 addr = row*64 + 8*(chunk ^ (row&7)).
// Staged via global_load_lds with PRE-SWIZZLED per-lane global source (linear LDS dest).
// Output addr = (m>>8)*cs_hi + (m&255)*cs_lo + (n>>6)*csz + (n&63)
//   csz=64: plain row-major (ld = cs_lo); csz=16384: QKV [b][h,j][t][64] scatter.
// XCD-chunked: xcd=d&7, slot=d>>3, bm=xcd*64+slot/nby, bn=slot%nby ->
//   the nby n-blocks of one m-tile run concurrently on one XCD => A re-read hits L2.
template<int NF, typename TC, typename TR>
__global__ __launch_bounds__(256,3) void mgemm2_k(
    const u16* __restrict__ A, int lda,
    const u16* __restrict__ Bt, int ldb,
    TC* __restrict__ C, long cs_hi, int cs_lo, int csz,
    const TR* __restrict__ R,
    const float* __restrict__ bias,
    int N, int Nstore, int K, float beta, int relu, int nby)
{
  constexpr int BN = NF*32;
  __shared__ __align__(16) u16 As[128*64];     // 16 KB
  __shared__ __align__(16) u16 Bs[BN*64];      // NF=6: 24 KB, NF=5: 20 KB
  const int d = blockIdx.x;
  const int xcd = d&7, slot = d>>3;
  const int bm = xcd*64 + slot/nby;
  const int bn = slot - (slot/nby)*nby;
  const int m0 = bm*128, n0 = bn*BN;
  const int tid = threadIdx.x;
  const int w = tid>>6, lane = tid&63;
  const int g4 = lane>>4, l16 = lane&15;
  const int wr = w>>1, wc = w&1;
  // staging source geometry (pre-swizzled): chunk q covers rows 8q..8q+7;
  // lane l -> row 8q+(l>>3), stored 16B-slot (l&7) holds logical k-chunk (l&7)^(l>>3).
  const int srow = lane>>3;
  const int sc8  = ((lane&7) ^ srow) * 8;
  const u16* aSrc[4];
#pragma unroll
  for(int i=0;i<4;i++)
    aSrc[i] = A + (size_t)(m0 + 8*(w+4*i) + srow)*lda + sc8;
  const u16* bSrc[NF];
#pragma unroll
  for(int i=0;i<NF;i++)
    bSrc[i] = Bt + (size_t)(n0 + 8*(w+4*i) + srow)*ldb + sc8;

  f32x4 fz = {0.f,0.f,0.f,0.f};
  f32x4 acc[4][NF];
#pragma unroll
  for(int i=0;i<4;i++)
#pragma unroll
    for(int j=0;j<NF;j++) acc[i][j]=fz;

  const int sxor = l16&7;
  for(int k0=0;k0<K;k0+=64){
    // issue async stages (A: 4 chunks/wave, B: NF chunks/wave)
#pragma unroll
    for(int i=0;i<4;i++)  gload16(aSrc[i] + k0, &As[(w+4*i)*512]);
#pragma unroll
    for(int i=0;i<NF;i++) gload16(bSrc[i] + k0, &Bs[(w+4*i)*512]);
    __syncthreads();                       // compiler drains vmcnt before barrier
#pragma unroll
    for(int ks=0; ks<2; ++ks){
      s16x8 av[4];
#pragma unroll
      for(int mf=0;mf<4;mf++){
        int Rr_ = wr*64 + mf*16 + l16;
        av[mf] = *(const s16x8*)&As[Rr_*64 + 8*((ks*4+g4) ^ sxor)];
      }
      s16x8 bv[NF];
#pragma unroll
      for(int nf=0;nf<NF;nf++){
        int Rn = wc*(NF*16) + nf*16 + l16;
        bv[nf] = *(const s16x8*)&Bs[Rn*64 + 8*((ks*4+g4) ^ sxor)];
      }
#pragma unroll
      for(int mf=0;mf<4;mf++)
#pragma unroll
        for(int nf=0;nf<NF;nf++)
          acc[mf][nf] = __builtin_amdgcn_mfma_f32_16x16x32_bf16(av[mf], bv[nf], acc[mf][nf], 0,0,0);
    }
    __syncthreads();                       // all frag reads done before restage
  }
  // epilogue: D layout col=lane&15, row=(lane>>4)*4+i
#pragma unroll
  for(int mf=0;mf<4;mf++)
#pragma unroll
    for(int i=0;i<4;i++){
      int m = m0 + wr*64 + mf*16 + g4*4 + i;
      long rowoff = (long)(m>>8)*cs_hi + (long)(m&255)*cs_lo;
#pragma unroll
      for(int nf=0;nf<NF;nf++){
        int gn = n0 + wc*(NF*16) + nf*16 + l16;
        if(gn < Nstore){
          long addr = rowoff + (long)(gn>>6)*csz + (gn&63);
          float v = 0.f;
          if(gn < N){
            v = acc[mf][nf][i];
            if(R)    v += beta*cvt(R[addr]);
            if(bias) v += bias[gn];
            if(relu) v  = fmaxf(v, 0.f);
          }
          stv(C + addr, v);
        }
      }
    }
}

// ---------------- MFMA causal flash attention: one block per (b,h), T=256, HS=64 ----------------
// QKV packed [B,H,{q,k,v},T,64] bf16: Qb = QKV + bh*49152, K at +16384, V at +32768.
__global__ __launch_bounds__(256,2) void mattn_k(const u16* __restrict__ QKV,
                                                 u16* __restrict__ O)
{
  __shared__ __align__(16) u16 Ks[64*64];    // [s][d], byte = s*128+2d ^ ((s&7)<<4)
  __shared__ __align__(16) u16 Vts[64*64];   // [d][s], byte = d*128+2s ^ ((d&7)<<4)
  __shared__ __align__(16) u16 Ps[4*4096];   // per-wave [m][s], byte = m*128+2s ^ ((m&7)<<4)
  const int bh = blockIdx.x;
  const int b = bh/6, h = bh - b*6;
  const u16* Qb = QKV + (size_t)bh*49152;
  const u16* Kb = Qb + 16384;
  const u16* Vb = Qb + 32768;
  const int tid = threadIdx.x;
  const int w = tid>>6, lane = tid&63;
  const int g4 = lane>>4, l16 = lane&15;
  char* PB = (char*)&Ps[w*4096];
  const int swz = (l16&7)<<4;

  s16x8 qf[4][2];
#pragma unroll
  for(int mi=0;mi<4;mi++)
#pragma unroll
    for(int ks=0;ks<2;ks++)
      qf[mi][ks] = *(const s16x8*)(Qb + (size_t)(w*64 + mi*16 + l16)*64 + ks*32 + g4*8);

  f32x4 fzv = {0.f,0.f,0.f,0.f};
  f32x4 o[4][4];
#pragma unroll
  for(int mf=0;mf<4;mf++)
#pragma unroll
    for(int df=0;df<4;df++) o[mf][df]=fzv;
  float mrun[4], lrun[4];
#pragma unroll
  for(int mi=0;mi<4;mi++){ mrun[mi]=-1e30f; lrun[mi]=0.f; }

  for(int st=0; st<4; ++st){
    if(st) __syncthreads();
#pragma unroll
    for(int it=0; it<2; ++it){
      int c = tid + 256*it;
      int s = c>>3, d0 = (c&7)*8;
      uint4 ld = *(const uint4*)(Kb + (size_t)(st*64+s)*64 + d0);
      int byte = s*128 + d0*2; byte ^= (s&7)<<4;
      *(uint4*)((char*)Ks + byte) = ld;
    }
#pragma unroll
    for(int it=0; it<2; ++it){
      int c = tid + 256*it;
      int s = c&63, d0 = (c>>6)*8;
      uint4 ld = *(const uint4*)(Vb + (size_t)(st*64+s)*64 + d0);
#pragma unroll
      for(int jj=0; jj<4; ++jj){
        u32 ww = (jj==0)?ld.x:(jj==1)?ld.y:(jj==2)?ld.z:ld.w;
        int d = d0 + 2*jj;
        int byte0 = d*128 + s*2;     byte0 ^= (d&7)<<4;
        int byte1 = (d+1)*128 + s*2; byte1 ^= ((d+1)&7)<<4;
        *(u16*)((char*)Vts + byte0) = (u16)(ww & 0xffffu);
        *(u16*)((char*)Vts + byte1) = (u16)(ww >> 16);
      }
    }
    __syncthreads();
    if(w < st) continue;

    f32x4 sc[4][4];
#pragma unroll
    for(int sf=0; sf<4; ++sf){
      int row = sf*16 + l16;
      s16x8 kf0 = *(const s16x8*)((char*)Ks + ((row*128 + g4*16) ^ swz));
      s16x8 kf1 = *(const s16x8*)((char*)Ks + ((row*128 + 64 + g4*16) ^ swz));
#pragma unroll
      for(int mi=0; mi<4; ++mi){
        f32x4 t = __builtin_amdgcn_mfma_f32_16x16x32_bf16(kf0, qf[mi][0], fzv, 0,0,0);
        sc[sf][mi] = __builtin_amdgcn_mfma_f32_16x16x32_bf16(kf1, qf[mi][1], t, 0,0,0);
      }
    }
    float alpha[4];
#pragma unroll
    for(int mi=0; mi<4; ++mi){
      int mloc = mi*16 + l16;
      float rmax = -3.0e38f;
#pragma unroll
      for(int sf=0; sf<4; ++sf)
#pragma unroll
        for(int i=0;i<4;i++){
          float vv = sc[sf][mi][i]*0.125f;
          if(st==w && (sf*16 + g4*4 + i) > mloc) vv = -1e30f;
          sc[sf][mi][i] = vv;
          rmax = fmaxf(rmax, vv);
        }
      rmax = fmaxf(rmax, __shfl_xor(rmax, 16, 64));
      rmax = fmaxf(rmax, __shfl_xor(rmax, 32, 64));
      float mnew = fmaxf(mrun[mi], rmax);
      float al = __expf(mrun[mi] - mnew);
      mrun[mi] = mnew;
      float ls = 0.f;
#pragma unroll
      for(int sf=0; sf<4; ++sf){
        float p0 = __expf(sc[sf][mi][0]-mnew);
        float p1 = __expf(sc[sf][mi][1]-mnew);
        float p2 = __expf(sc[sf][mi][2]-mnew);
        float p3 = __expf(sc[sf][mi][3]-mnew);
        ls += p0+p1+p2+p3;
        ushort4 pk; pk.x=f2bf(p0); pk.y=f2bf(p1); pk.z=f2bf(p2); pk.w=f2bf(p3);
        int byte = mloc*128 + sf*32 + g4*8; byte ^= (l16&7)<<4;
        *(ushort4*)(PB + byte) = pk;
      }
      ls += __shfl_xor(ls, 16, 64);
      ls += __shfl_xor(ls, 32, 64);
      lrun[mi] = lrun[mi]*al + ls;
      alpha[mi] = al;
    }
#pragma unroll
    for(int mf=0; mf<4; ++mf)
#pragma unroll
      for(int i=0;i<4;i++){
        float at = __shfl(alpha[mf], g4*4 + i, 64);
#pragma unroll
        for(int df=0; df<4; ++df) o[mf][df][i] *= at;
      }
    s16x8 vbf[4][2];
#pragma unroll
    for(int df=0; df<4; ++df){
      int row = df*16 + l16;
      vbf[df][0] = *(const s16x8*)((char*)Vts + ((row*128 + g4*16) ^ swz));
      vbf[df][1] = *(const s16x8*)((char*)Vts + ((row*128 + 64 + g4*16) ^ swz));
    }
#pragma unroll
    for(int mf=0; mf<4; ++mf){
      int row = mf*16 + l16;
      s16x8 pa0 = *(const s16x8*)(PB + ((row*128 + g4*16) ^ swz));
      s16x8 pa1 = *(const s16x8*)(PB + ((row*128 + 64 + g4*16) ^ swz));
#pragma unroll
      for(int df=0; df<4; ++df){
        f32x4 t = __builtin_amdgcn_mfma_f32_16x16x32_bf16(pa0, vbf[df][0], o[mf][df], 0,0,0);
        o[mf][df] = __builtin_amdgcn_mfma_f32_16x16x32_bf16(pa1, vbf[df][1], t, 0,0,0);
      }
    }
  }
#pragma unroll
  for(int mf=0; mf<4; ++mf)
#pragma unroll
    for(int i=0;i<4;i++){
      float lt = __shfl(lrun[mf], g4*4 + i, 64);
      float rl = 1.f/lt;
      u16* orow = O + ((size_t)(b*256 + w*64 + mf*16 + g4*4 + i))*384 + h*64;
#pragma unroll
      for(int df=0; df<4; ++df)
        orow[df*16 + l16] = f2bf(o[mf][df][i]*rl);
    }
}

// ================= Newton-Schulz orthogonalization, stream-ordered =================
__global__ __launch_bounds__(256) void fpart_k(const float* __restrict__ W0,
                                               const float* __restrict__ W1,
                                               float* __restrict__ part)
{
  int b = blockIdx.x; int z = b/24, seg = b - z*24;
  const float* W = (z ? W1 : W0) + seg*6144;
  int tid = threadIdx.x;
  float s = 0.f;
  for(int i=tid;i<6144;i+=256){ float v=W[i]; s+=v*v; }
#pragma unroll
  for(int off=32; off>0; off>>=1) s += __shfl_down(s, off, 64);
  __shared__ float red[4];
  if((tid&63)==0) red[tid>>6]=s;
  __syncthreads();
  if(tid==0) part[b] = red[0]+red[1]+red[2]+red[3];
}

__global__ __launch_bounds__(64) void fcomb_k(const float* __restrict__ part,
                                              float* __restrict__ invb)
{
  int lane = threadIdx.x;
  float v = 0.f;
  if(lane < 24) v = part[lane];
  else if(lane >= 32 && lane < 56) v = part[lane - 8];
#pragma unroll
  for(int off=1; off<32; off<<=1) v += __shfl_xor(v, off, 64);
  if(lane==0)  invb[0] = rsqrtf(v);
  if(lane==32) invb[1] = rsqrtf(v);
}

__global__ __launch_bounds__(256) void nsinit_k(const float* __restrict__ W0,
                                                const float* __restrict__ W1,
                                                const float* __restrict__ invb,
                                                u16* __restrict__ XB)
{
  int b = blockIdx.x; int z = b/24, p = b - z*24, cp0 = p*16;
  const float* W = z ? W1 : W0;
  float inv = invb[z];
  u16* base = XB + (size_t)z*589824;
  u16* xh = base;            u16* xl = base + 147456;
  u16* th = base + 294912;   u16* tl = base + 442368;
  int tid = threadIdx.x;
  for(int idx=tid; idx<6144; idx+=256){
    int r = idx>>4, j = idx&15;
    float v = W[r*384 + cp0 + j]*inv;
    u16 hh = f2bf(v);
    xh[p*6144 + idx] = hh;
    xl[p*6144 + idx] = f2bf(v - bf2f(hh));
  }
  for(int idx=tid; idx<6144; idx+=256){
    int j = idx/384, r = idx - j*384;
    float v = W[(cp0+j)*384 + r]*inv;
    u16 hh = f2bf(v);
    th[p*6144 + r*16 + j] = hh;
    tl[p*6144 + r*16 + j] = f2bf(v - bf2f(hh));
  }
}

static __device__ __forceinline__ void ns_mm(
    const u16* __restrict__ Agh, const u16* __restrict__ Agl,
    u16* AhL, u16* AlL, const u16* BThL, const u16* BTlL,
    int tid, f32x4 acc[4])
{
  const int w = tid>>6, lane = tid&63, g4 = lane>>4, l16 = lane&15;
  const int o0 = (tid>>1)*24 + (tid&1)*8;
  const int o1 = o0 + 4608;
  const s16x8 z8 = {0,0,0,0,0,0,0,0};
  f32x4 fz = {0.f,0.f,0.f,0.f};
#pragma unroll
  for(int i=0;i<4;i++) acc[i]=fz;
  {
    uint4 h0 = *(const uint4*)(Agh + tid*8);
    uint4 h1 = *(const uint4*)(Agh + (384+tid)*8);
    uint4 l0 = *(const uint4*)(Agl + tid*8);
    uint4 l1 = *(const uint4*)(Agl + (384+tid)*8);
    *(uint4*)&AhL[o0] = h0; *(uint4*)&AhL[o1] = h1;
    *(uint4*)&AlL[o0] = l0; *(uint4*)&AlL[o1] = l1;
  }
  __syncthreads();
  for(int c=0;c<24;c++){
    uint4 nh0, nh1, nl0, nl1;
    if(c<23){
      const u16* ph = Agh + (c+1)*6144;
      const u16* pl = Agl + (c+1)*6144;
      nh0 = *(const uint4*)(ph + tid*8);
      nh1 = *(const uint4*)(ph + (384+tid)*8);
      nl0 = *(const uint4*)(pl + tid*8);
      nl1 = *(const uint4*)(pl + (384+tid)*8);
    }
    s16x8 bh = z8, bl = z8;
    if(g4<2){
      bh = *(const s16x8*)&BThL[l16*392 + c*16 + g4*8];
      bl = *(const s16x8*)&BTlL[l16*392 + c*16 + g4*8];
    }
#pragma unroll
    for(int tt=0;tt<4;tt++){
      int rb = 64*w + 16*tt + l16;
      s16x8 ah = z8, al = z8;
      if(g4<2){
        ah = *(const s16x8*)&AhL[rb*24 + g4*8];
        al = *(const s16x8*)&AlL[rb*24 + g4*8];
      }
      acc[tt] = __builtin_amdgcn_mfma_f32_16x16x32_bf16(ah, bh, acc[tt], 0,0,0);
      acc[tt] = __builtin_amdgcn_mfma_f32_16x16x32_bf16(ah, bl, acc[tt], 0,0,0);
      acc[tt] = __builtin_amdgcn_mfma_f32_16x16x32_bf16(al, bh, acc[tt], 0,0,0);
    }
    __syncthreads();
    if(c<23){
      *(uint4*)&AhL[o0] = nh0; *(uint4*)&AhL[o1] = nh1;
      *(uint4*)&AlL[o0] = nl0; *(uint4*)&AlL[o1] = nl1;
      __syncthreads();
    }
  }
}

__global__ __launch_bounds__(384) void nsit_k(u16* __restrict__ XB,
                                              u16* __restrict__ QT,
                                              int it, int niter, int nq)
{
  __shared__ __align__(16) u16 AhL[384*24];
  __shared__ __align__(16) u16 AlL[384*24];
  __shared__ __align__(16) u16 BTh[16*392];
  __shared__ __align__(16) u16 BTl[16*392];
  const int blk = blockIdx.x;
  const int z = blk/24, p = blk - z*24, cp0 = p*16;
  const int tid = threadIdx.x;
  const int w = tid>>6, lane = tid&63, g4 = lane>>4, l16 = lane&15;
  const int rs = it&1, ws2 = rs^1;
  const u16* bin  = XB + (size_t)rs*1179648  + (size_t)z*589824;
  u16*       bout = XB + (size_t)ws2*1179648 + (size_t)z*589824;
  const u16* Xh  = bin;            const u16* Xl  = bin + 147456;
  const u16* Th  = bin + 294912;   const u16* Tl  = bin + 442368;

  {
    const u16* sh = Xh + p*6144;
    const u16* sl = Xl + p*6144;
    for(int i=tid; i<768; i+=384){
      int k = i>>1, n0 = (i&1)*8;
      uint4 vh = *(const uint4*)(sh + i*8);
      uint4 vl = *(const uint4*)(sl + i*8);
#pragma unroll
      for(int j=0;j<8;j++){
        BTh[(n0+j)*392 + k] = ((u16*)&vh)[j];
        BTl[(n0+j)*392 + k] = ((u16*)&vl)[j];
      }
    }
  }
  __syncthreads();

  const bool quint = (it < nq);
  f32x4 acc[4], gsv[4];

  ns_mm(Th, Tl, AhL, AlL, BTh, BTl, tid, acc);
  if(quint){
#pragma unroll
    for(int tt=0;tt<4;tt++){
      gsv[tt] = acc[tt];
      int m0 = 64*w + 16*tt + g4*4;
      ushort4 h4, l4;
#pragma unroll
      for(int i=0;i<4;i++){
        float v = acc[tt][i];
        u16 hh = f2bf(v);
        ((u16*)&h4)[i]=hh; ((u16*)&l4)[i]=f2bf(v - bf2f(hh));
      }
      *(ushort4*)&BTh[l16*392 + m0] = h4;
      *(ushort4*)&BTl[l16*392 + m0] = l4;
    }
    __syncthreads();
    ns_mm(Xh, Xl, AhL, AlL, BTh, BTl, tid, acc);
#pragma unroll
    for(int tt=0;tt<4;tt++){
      int m0 = 64*w + 16*tt + g4*4;
      ushort4 h4, l4;
#pragma unroll
      for(int i=0;i<4;i++){
        float v = acc[tt][i];
        u16 hh = f2bf(v);
        ((u16*)&h4)[i]=hh; ((u16*)&l4)[i]=f2bf(v - bf2f(hh));
      }
      *(ushort4*)&BTh[l16*392 + m0] = h4;
      *(ushort4*)&BTl[l16*392 + m0] = l4;
    }
    __syncthreads();
    ns_mm(Th, Tl, AhL, AlL, BTh, BTl, tid, acc);
    __syncthreads();
#pragma unroll
    for(int tt=0;tt<4;tt++){
      int m0 = 64*w + 16*tt + g4*4;
      ushort4 h4, l4;
#pragma unroll
      for(int i=0;i<4;i++){
        float v = fmaf(2.0315f, acc[tt][i], -4.7750f*(gsv[tt][i]))
                + ((m0+i)==(cp0+l16) ? 3.4445f : 0.f);
        u16 hh = f2bf(v);
        ((u16*)&h4)[i]=hh; ((u16*)&l4)[i]=f2bf(v - bf2f(hh));
      }
      *(ushort4*)&BTh[l16*392 + m0] = h4;
      *(ushort4*)&BTl[l16*392 + m0] = l4;
    }
    __syncthreads();
  } else {
#pragma unroll
    for(int tt=0;tt<4;tt++){
      int m0 = 64*w + 16*tt + g4*4;
      ushort4 h4, l4;
#pragma unroll
      for(int i=0;i<4;i++){
        float v = -0.5f*acc[tt][i] + ((m0+i)==(cp0+l16) ? 1.5f : 0.f);
        u16 hh = f2bf(v);
        ((u16*)&h4)[i]=hh; ((u16*)&l4)[i]=f2bf(v - bf2f(hh));
      }
      *(ushort4*)&BTh[l16*392 + m0] = h4;
      *(ushort4*)&BTl[l16*392 + m0] = l4;
    }
    __syncthreads();
  }
  ns_mm(Xh, Xl, AhL, AlL, BTh, BTl, tid, acc);

  if(it == niter-1){
    u16* q = QT + (size_t)z*147456 + (size_t)(cp0+l16)*384;
#pragma unroll
    for(int tt=0;tt<4;tt++){
      int m0 = 64*w + 16*tt + g4*4;
      ushort4 h4;
#pragma unroll
      for(int i=0;i<4;i++) ((u16*)&h4)[i] = f2bf(acc[tt][i]);
      *(ushort4*)&q[m0] = h4;
    }
  } else {
    u16* oXh = bout + p*6144;            u16* oXl = bout + 147456 + p*6144;
    u16* oTh = bout + 294912;            u16* oTl = bout + 442368;
#pragma unroll
    for(int tt=0;tt<4;tt++){
      int m0 = 64*w + 16*tt + g4*4;
      ushort4 h4, l4;
#pragma unroll
      for(int i=0;i<4;i++){
        float v = acc[tt][i];
        u16 hh = f2bf(v);
        ((u16*)&h4)[i]=hh; ((u16*)&l4)[i]=f2bf(v - bf2f(hh));
        oXh[(m0+i)*16 + l16] = hh;
        oXl[(m0+i)*16 + l16] = ((u16*)&l4)[i];
      }
      size_t to = (size_t)(4*w+tt)*6144 + (size_t)(cp0+l16)*16 + g4*4;
      *(ushort4*)&oTh[to] = h4;
      *(ushort4*)&oTl[to] = l4;
    }
  }
}

// ---------------- host-side orchestration ----------------
extern "C" void kernel_launch(void* const* d_in, const int* in_sizes, int n_in,
                              void* d_out, int out_size, void* d_ws, size_t ws_size,
                              hipStream_t stream)
{
  const float* x      = (const float*)d_in[0];
  const float* Wq     = (const float*)d_in[1];
  const float* Wk     = (const float*)d_in[2];
  const float* Wv     = (const float*)d_in[3];
  const float* Wp     = (const float*)d_in[4];
  const float* bp     = (const float*)d_in[5];
  const float* scale1 = (const float*)d_in[6];
  const float* scale2 = (const float*)d_in[7];
  const float* W1     = (const float*)d_in[8];
  const float* b1     = (const float*)d_in[9];
  const float* W2     = (const float*)d_in[10];
  const float* b2     = (const float*)d_in[11];
  const float* Wo_in  = (const float*)d_in[12];
  const float* Wo_out = (const float*)d_in[13];

  // ---- workspace layout ----
  char* ws = (char*)d_ws;
  u16* XB   = (u16*)(ws + 0);                 // NS X buffers (4.7 MB)
  u16* Wqkv = (u16*)(ws + 4719104L);          // [h][{q,k,v}][64][384] bf16
  u16* WpT  = (u16*)(ws + 5603840L);          // [384][384]
  u16* W1T  = (u16*)(ws + 5898752L);          // [307][384]
  u16* W2T  = (u16*)(ws + 6134528L);          // [384][320] (k-padded with zeros)
  u16* QT   = (u16*)(ws + 6380288L);          // orth(Wo_in)^T, orth(Wo_out)^T bf16
  float* part = (float*)(ws + 6970112L);      // 48 floats
  float* invb = (float*)(ws + 6970496L);      // 2 floats
  u16* h1b  = (u16*)(ws + 8388608L);          // S0: h1 -> h6                (48 MB)
  u16* qkvb = (u16*)(ws + 58720256L);         // S1-S3: qkv packed -> h2/h3/h4 (144 MB)
  u16* atb  = (u16*)(ws + 209715200L);        // S4: attn_cat [65536][384] -> h5 [65536][320]
  u16* h2b = qkvb;
  u16* h3b = qkvb + 25165824L;
  u16* h4b = qkvb + 50331648L;
  u16* h5b = atb;
  u16* h6b = h1b;

  // --- weight transpose+cast ---
  tcast_k<<<dim3(12, 2,6),256,0,stream>>>(Wq,24576L, Wqkv,        73728L, 384, 64,384);
  tcast_k<<<dim3(12, 2,6),256,0,stream>>>(Wk,24576L, Wqkv+24576L, 73728L, 384, 64,384);
  tcast_k<<<dim3(12, 2,6),256,0,stream>>>(Wv,24576L, Wqkv+49152L, 73728L, 384, 64,384);
  tcast_k<<<dim3(12,12,1),256,0,stream>>>(Wp,0L,     WpT,0L,     384,384,384);
  tcast_k<<<dim3(12,10,1),256,0,stream>>>(W1,0L,     W1T,0L,     384,307,384);
  tcast_k<<<dim3(10,12,1),256,0,stream>>>(W2,0L,     W2T,0L,     307,384,320);

  // --- orth via stream-ordered Newton-Schulz chain (10 quintic + 5 cubic) ---
  const int NITER = 15, NQ = 10;
  fpart_k<<<48,256,0,stream>>>(Wo_in, Wo_out, part);
  fcomb_k<<<1,64,0,stream>>>(part, invb);
  nsinit_k<<<48,256,0,stream>>>(Wo_in, Wo_out, invb, XB);
  for(int it=0; it<NITER; ++it)
    nsit_k<<<48,384,0,stream>>>(XB, QT, it, NITER, NQ);

  // --- main path: bf16 activations + MFMA, BN=192 tiles, gload_lds staging ---
  rms_k<float,u16><<<16384,256,0,stream>>>(x, scale1, h1b);
  // QKV: N=1152 in 6 n-tiles, XCD-co-located; scatter to [b][h,j][t][64]
  mgemm2_k<6,u16,float><<<3072,256,0,stream>>>(
      h1b,384,  Wqkv,384,
      qkvb, 294912L,64,16384,
      (const float*)nullptr, nullptr,
      1152,1152,384, 0.f,0, 6);
  mattn_k<<<1536,256,0,stream>>>(qkvb, atb);
  // h2 = attn@Wp + bp + h1
  mgemm2_k<6,u16,u16><<<1024,256,0,stream>>>(
      atb,384,  WpT,384,
      h2b, 98304L,384,64,
      h1b, bp,
      384,384,384, 1.f,0, 2);
  rms_k<u16,u16><<<16384,256,0,stream>>>(h2b, scale2, h3b);
  // h4 = h3 @ orth(Wo_in)
  mgemm2_k<6,u16,float><<<1024,256,0,stream>>>(
      h3b,384,  QT,384,
      h4b, 98304L,384,64,
      (const float*)nullptr, nullptr,
      384,384,384, 0.f,0, 2);
  // h5 = relu(h4@W1 + b1), N=307 stored ld 320, cols 307..319 zeroed
  mgemm2_k<5,u16,float><<<1024,256,0,stream>>>(
      h4b,384,  W1T,384,
      h5b, 81920L,320,64,
      (const float*)nullptr, b1,
      307,320,384, 0.f,1, 2);
  // h6 = h5@W2 + b2  (K padded to 320)
  mgemm2_k<6,u16,float><<<1024,256,0,stream>>>(
      h5b,320,  W2T,320,
      h6b, 98304L,384,64,
      (const float*)nullptr, b2,
      384,384,320, 0.f,0, 2);
  // out = h6 @ orth(Wo_out) + h6 -> fp32 d_out
  mgemm2_k<6,float,u16><<<1024,256,0,stream>>>(
      h6b,384,  QT+147456,384,
      (float*)d_out, 98304L,384,64,
      h6b, nullptr,
      384,384,384, 1.f,0, 2);

  (void)in_sizes; (void)n_in; (void)ws_size; (void)out_size;
}

// Round 7
// 1569.367 us; speedup vs baseline: 1.0835x; 1.0164x over previous
//
#include <hip/hip_runtime.h>
#include <hip/hip_cooperative_groups.h>

namespace cg = cooperative_groups;

typedef unsigned short u16;
typedef unsigned int   u32;
typedef short s16x8 __attribute__((ext_vector_type(8)));   // 8 bf16 lanes for MFMA
typedef float f32x4 __attribute__((ext_vector_type(4)));

// ---- bf16 helpers (store with round-to-nearest-even) ----
static __device__ __forceinline__ float bf2f(u16 v){ return __uint_as_float(((u32)v)<<16); }
static __device__ __forceinline__ u16 f2bf(float f){
  u32 u = __float_as_uint(f);
  u32 r = (u + 0x7fffu + ((u>>16)&1u)) >> 16;
  return (u16)r;
}
static __device__ __forceinline__ float cvt(float v){ return v; }
static __device__ __forceinline__ float cvt(u16 v){ return bf2f(v); }
static __device__ __forceinline__ void stv(float* p, float v){ *p = v; }
static __device__ __forceinline__ void stv(u16* p, float v){ *p = f2bf(v); }

static __device__ __forceinline__ void ld2(const float* p, float& a, float& b){
  float2 t = *(const float2*)p; a=t.x; b=t.y;
}
static __device__ __forceinline__ void ld2(const u16* p, float& a, float& b){
  u32 t = *(const u32*)p; a = __uint_as_float(t<<16); b = __uint_as_float(t & 0xffff0000u);
}
static __device__ __forceinline__ void st2(float* p, float a, float b){
  float2 t; t.x=a; t.y=b; *(float2*)p = t;
}
static __device__ __forceinline__ void st2(u16* p, float a, float b){
  *(u32*)p = ((u32)f2bf(a)) | (((u32)f2bf(b))<<16);
}

// async global->LDS, 16B per lane, dest = wave-uniform base + lane*16
static __device__ __forceinline__ void gload16(const u16* g, u16* l){
  __builtin_amdgcn_global_load_lds(
      (const __attribute__((address_space(1))) u32*)(const void*)g,
      (__attribute__((address_space(3))) u32*)(void*)l, 16, 0, 0);
}

// ---------------- RMSNorm: O = X / rms(X) * scale, vectorized 2-wide ----------------
template<typename TI, typename TO>
__global__ __launch_bounds__(256) void rms_k(const TI* __restrict__ X,
                                             const float* __restrict__ scale,
                                             TO* __restrict__ O)
{
  int row = blockIdx.x*4 + (threadIdx.x>>6);
  int lane = threadIdx.x&63;
  const TI* xr = X + (size_t)row*384;
  float v[6]; float ss = 0.f;
#pragma unroll
  for(int i=0;i<3;i++){
    ld2(xr + 2*lane + 128*i, v[2*i], v[2*i+1]);
    ss += v[2*i]*v[2*i] + v[2*i+1]*v[2*i+1];
  }
#pragma unroll
  for(int off=32; off>0; off>>=1) ss += __shfl_down(ss, off, 64);
  ss = __shfl(ss, 0, 64);
  float r = rsqrtf(ss*(1.0f/384.0f)+1e-6f);
  TO* orow = O + (size_t)row*384;
#pragma unroll
  for(int i=0;i<3;i++){
    int c = 2*lane + 128*i;
    st2(orow + c, v[2*i]*r*scale[c], v[2*i+1]*r*scale[c+1]);
  }
}

// ---------------- transpose + cast fp32 -> bf16: Out[c][r] = (r<Rr ? In[r][c] : 0) ----------------
__global__ __launch_bounds__(256) void tcast_k(const float* __restrict__ In, long isz,
                                               u16* __restrict__ Out, long osz,
                                               int Rr, int Cc, int ldo)
{
  __shared__ float t[32][33];
  const int z = blockIdx.z;
  const float* I = In + (long)z*isz;
  u16* Oz = Out + (long)z*osz;
  const int r0 = blockIdx.x*32, c0 = blockIdx.y*32;
  const int tx = threadIdx.x&31, ty = threadIdx.x>>5;
#pragma unroll
  for(int rr=ty; rr<32; rr+=8){
    int r = r0+rr, c = c0+tx;
    t[rr][tx] = (r<Rr && c<Cc) ? I[(size_t)r*Cc + c] : 0.f;
  }
  __syncthreads();
#pragma unroll
  for(int cc=ty; cc<32; cc+=8){
    int c = c0+cc, r = r0+tx;
    if(c<Cc && r<ldo) Oz[(size_t)c*ldo + r] = f2bf(t[tx][cc]);
  }
}

// ============ bf16 MFMA GEMM, BM=128 x BN=NF*32, BK=64, global_load_lds staging ============
// NF=2 -> BN=64: acc[4][2]=32 AGPR + ~60 arch VGPR -> 4 waves/SIMD (unified file!),
// 4 blocks/CU, grid 512*nby -> 12+ blocks/CU for latency overlap across blocks.
// LDS rows = 64 u16 (128 B), XOR-swizzled: u16 addr = row*64 + 8*(chunk ^ (row&7)).
// Staged via global_load_lds with PRE-SWIZZLED per-lane global source (linear LDS dest).
// Output addr = (m>>8)*cs_hi + (m&255)*cs_lo + (n>>6)*csz + (n&63)
//   csz=64: plain row-major (ld = cs_lo); csz=16384: QKV [b][h,j][t][64] scatter.
// XCD-chunked: xcd=d&7, slot=d>>3, bm=xcd*64+slot/nby, bn=slot%nby ->
//   the nby n-blocks of one m-tile run concurrently on one XCD => A re-read hits L2.
template<int NF, typename TC, typename TR>
__global__ __launch_bounds__(256,4) void mgemm2_k(
    const u16* __restrict__ A, int lda,
    const u16* __restrict__ Bt, int ldb,
    TC* __restrict__ C, long cs_hi, int cs_lo, int csz,
    const TR* __restrict__ R,
    const float* __restrict__ bias,
    int N, int Nstore, int K, float beta, int relu, int nby)
{
  constexpr int BN = NF*32;
  __shared__ __align__(16) u16 As[128*64];     // 16 KB
  __shared__ __align__(16) u16 Bs[BN*64];      // NF=2: 8 KB
  const int d = blockIdx.x;
  const int xcd = d&7, slot = d>>3;
  const int bm = xcd*64 + slot/nby;
  const int bn = slot - (slot/nby)*nby;
  const int m0 = bm*128, n0 = bn*BN;
  const int tid = threadIdx.x;
  const int w = tid>>6, lane = tid&63;
  const int g4 = lane>>4, l16 = lane&15;
  const int wr = w>>1, wc = w&1;
  // staging source geometry (pre-swizzled): chunk q covers rows 8q..8q+7;
  // lane l -> row 8q+(l>>3), stored 16B-slot (l&7) holds logical k-chunk (l&7)^(l>>3).
  const int srow = lane>>3;
  const int sc8  = ((lane&7) ^ srow) * 8;
  const u16* aSrc[4];
#pragma unroll
  for(int i=0;i<4;i++)
    aSrc[i] = A + (size_t)(m0 + 8*(w+4*i) + srow)*lda + sc8;
  const u16* bSrc[NF];
#pragma unroll
  for(int i=0;i<NF;i++)
    bSrc[i] = Bt + (size_t)(n0 + 8*(w+4*i) + srow)*ldb + sc8;

  f32x4 fz = {0.f,0.f,0.f,0.f};
  f32x4 acc[4][NF];
#pragma unroll
  for(int i=0;i<4;i++)
#pragma unroll
    for(int j=0;j<NF;j++) acc[i][j]=fz;

  const int sxor = l16&7;
  for(int k0=0;k0<K;k0+=64){
    // issue async stages (A: 4 chunks/wave, B: NF chunks/wave)
#pragma unroll
    for(int i=0;i<4;i++)  gload16(aSrc[i] + k0, &As[(w+4*i)*512]);
#pragma unroll
    for(int i=0;i<NF;i++) gload16(bSrc[i] + k0, &Bs[(w+4*i)*512]);
    __syncthreads();                       // compiler drains vmcnt before barrier
#pragma unroll
    for(int ks=0; ks<2; ++ks){
      s16x8 av[4];
#pragma unroll
      for(int mf=0;mf<4;mf++){
        int Rr_ = wr*64 + mf*16 + l16;
        av[mf] = *(const s16x8*)&As[Rr_*64 + 8*((ks*4+g4) ^ sxor)];
      }
      s16x8 bv[NF];
#pragma unroll
      for(int nf=0;nf<NF;nf++){
        int Rn = wc*(NF*16) + nf*16 + l16;
        bv[nf] = *(const s16x8*)&Bs[Rn*64 + 8*((ks*4+g4) ^ sxor)];
      }
#pragma unroll
      for(int mf=0;mf<4;mf++)
#pragma unroll
        for(int nf=0;nf<NF;nf++)
          acc[mf][nf] = __builtin_amdgcn_mfma_f32_16x16x32_bf16(av[mf], bv[nf], acc[mf][nf], 0,0,0);
    }
    __syncthreads();                       // all frag reads done before restage
  }
  // epilogue: D layout col=lane&15, row=(lane>>4)*4+i
#pragma unroll
  for(int mf=0;mf<4;mf++)
#pragma unroll
    for(int i=0;i<4;i++){
      int m = m0 + wr*64 + mf*16 + g4*4 + i;
      long rowoff = (long)(m>>8)*cs_hi + (long)(m&255)*cs_lo;
#pragma unroll
      for(int nf=0;nf<NF;nf++){
        int gn = n0 + wc*(NF*16) + nf*16 + l16;
        if(gn < Nstore){
          long addr = rowoff + (long)(gn>>6)*csz + (gn&63);
          float v = 0.f;
          if(gn < N){
            v = acc[mf][nf][i];
            if(R)    v += beta*cvt(R[addr]);
            if(bias) v += bias[gn];
            if(relu) v  = fmaxf(v, 0.f);
          }
          stv(C + addr, v);
        }
      }
    }
}

// ---------------- MFMA causal flash attention: one block per (b,h), T=256, HS=64 ----------------
// QKV packed [B,H,{q,k,v},T,64] bf16: Qb = QKV + bh*49152, K at +16384, V at +32768.
__global__ __launch_bounds__(256,2) void mattn_k(const u16* __restrict__ QKV,
                                                 u16* __restrict__ O)
{
  __shared__ __align__(16) u16 Ks[64*64];    // [s][d], byte = s*128+2d ^ ((s&7)<<4)
  __shared__ __align__(16) u16 Vts[64*64];   // [d][s], byte = d*128+2s ^ ((d&7)<<4)
  __shared__ __align__(16) u16 Ps[4*4096];   // per-wave [m][s], byte = m*128+2s ^ ((m&7)<<4)
  const int bh = blockIdx.x;
  const int b = bh/6, h = bh - b*6;
  const u16* Qb = QKV + (size_t)bh*49152;
  const u16* Kb = Qb + 16384;
  const u16* Vb = Qb + 32768;
  const int tid = threadIdx.x;
  const int w = tid>>6, lane = tid&63;
  const int g4 = lane>>4, l16 = lane&15;
  char* PB = (char*)&Ps[w*4096];
  const int swz = (l16&7)<<4;

  s16x8 qf[4][2];
#pragma unroll
  for(int mi=0;mi<4;mi++)
#pragma unroll
    for(int ks=0;ks<2;ks++)
      qf[mi][ks] = *(const s16x8*)(Qb + (size_t)(w*64 + mi*16 + l16)*64 + ks*32 + g4*8);

  f32x4 fzv = {0.f,0.f,0.f,0.f};
  f32x4 o[4][4];
#pragma unroll
  for(int mf=0;mf<4;mf++)
#pragma unroll
    for(int df=0;df<4;df++) o[mf][df]=fzv;
  float mrun[4], lrun[4];
#pragma unroll
  for(int mi=0;mi<4;mi++){ mrun[mi]=-1e30f; lrun[mi]=0.f; }

  for(int st=0; st<4; ++st){
    if(st) __syncthreads();
#pragma unroll
    for(int it=0; it<2; ++it){
      int c = tid + 256*it;
      int s = c>>3, d0 = (c&7)*8;
      uint4 ld = *(const uint4*)(Kb + (size_t)(st*64+s)*64 + d0);
      int byte = s*128 + d0*2; byte ^= (s&7)<<4;
      *(uint4*)((char*)Ks + byte) = ld;
    }
#pragma unroll
    for(int it=0; it<2; ++it){
      int c = tid + 256*it;
      int s = c&63, d0 = (c>>6)*8;
      uint4 ld = *(const uint4*)(Vb + (size_t)(st*64+s)*64 + d0);
#pragma unroll
      for(int jj=0; jj<4; ++jj){
        u32 ww = (jj==0)?ld.x:(jj==1)?ld.y:(jj==2)?ld.z:ld.w;
        int d = d0 + 2*jj;
        int byte0 = d*128 + s*2;     byte0 ^= (d&7)<<4;
        int byte1 = (d+1)*128 + s*2; byte1 ^= ((d+1)&7)<<4;
        *(u16*)((char*)Vts + byte0) = (u16)(ww & 0xffffu);
        *(u16*)((char*)Vts + byte1) = (u16)(ww >> 16);
      }
    }
    __syncthreads();
    if(w < st) continue;

    f32x4 sc[4][4];
#pragma unroll
    for(int sf=0; sf<4; ++sf){
      int row = sf*16 + l16;
      s16x8 kf0 = *(const s16x8*)((char*)Ks + ((row*128 + g4*16) ^ swz));
      s16x8 kf1 = *(const s16x8*)((char*)Ks + ((row*128 + 64 + g4*16) ^ swz));
#pragma unroll
      for(int mi=0; mi<4; ++mi){
        f32x4 t = __builtin_amdgcn_mfma_f32_16x16x32_bf16(kf0, qf[mi][0], fzv, 0,0,0);
        sc[sf][mi] = __builtin_amdgcn_mfma_f32_16x16x32_bf16(kf1, qf[mi][1], t, 0,0,0);
      }
    }
    float alpha[4];
#pragma unroll
    for(int mi=0; mi<4; ++mi){
      int mloc = mi*16 + l16;
      float rmax = -3.0e38f;
#pragma unroll
      for(int sf=0; sf<4; ++sf)
#pragma unroll
        for(int i=0;i<4;i++){
          float vv = sc[sf][mi][i]*0.125f;
          if(st==w && (sf*16 + g4*4 + i) > mloc) vv = -1e30f;
          sc[sf][mi][i] = vv;
          rmax = fmaxf(rmax, vv);
        }
      rmax = fmaxf(rmax, __shfl_xor(rmax, 16, 64));
      rmax = fmaxf(rmax, __shfl_xor(rmax, 32, 64));
      float mnew = fmaxf(mrun[mi], rmax);
      float al = __expf(mrun[mi] - mnew);
      mrun[mi] = mnew;
      float ls = 0.f;
#pragma unroll
      for(int sf=0; sf<4; ++sf){
        float p0 = __expf(sc[sf][mi][0]-mnew);
        float p1 = __expf(sc[sf][mi][1]-mnew);
        float p2 = __expf(sc[sf][mi][2]-mnew);
        float p3 = __expf(sc[sf][mi][3]-mnew);
        ls += p0+p1+p2+p3;
        ushort4 pk; pk.x=f2bf(p0); pk.y=f2bf(p1); pk.z=f2bf(p2); pk.w=f2bf(p3);
        int byte = mloc*128 + sf*32 + g4*8; byte ^= (l16&7)<<4;
        *(ushort4*)(PB + byte) = pk;
      }
      ls += __shfl_xor(ls, 16, 64);
      ls += __shfl_xor(ls, 32, 64);
      lrun[mi] = lrun[mi]*al + ls;
      alpha[mi] = al;
    }
#pragma unroll
    for(int mf=0; mf<4; ++mf)
#pragma unroll
      for(int i=0;i<4;i++){
        float at = __shfl(alpha[mf], g4*4 + i, 64);
#pragma unroll
        for(int df=0; df<4; ++df) o[mf][df][i] *= at;
      }
    s16x8 vbf[4][2];
#pragma unroll
    for(int df=0; df<4; ++df){
      int row = df*16 + l16;
      vbf[df][0] = *(const s16x8*)((char*)Vts + ((row*128 + g4*16) ^ swz));
      vbf[df][1] = *(const s16x8*)((char*)Vts + ((row*128 + 64 + g4*16) ^ swz));
    }
#pragma unroll
    for(int mf=0; mf<4; ++mf){
      int row = mf*16 + l16;
      s16x8 pa0 = *(const s16x8*)(PB + ((row*128 + g4*16) ^ swz));
      s16x8 pa1 = *(const s16x8*)(PB + ((row*128 + 64 + g4*16) ^ swz));
#pragma unroll
      for(int df=0; df<4; ++df){
        f32x4 t = __builtin_amdgcn_mfma_f32_16x16x32_bf16(pa0, vbf[df][0], o[mf][df], 0,0,0);
        o[mf][df] = __builtin_amdgcn_mfma_f32_16x16x32_bf16(pa1, vbf[df][1], t, 0,0,0);
      }
    }
  }
#pragma unroll
  for(int mf=0; mf<4; ++mf)
#pragma unroll
    for(int i=0;i<4;i++){
      float lt = __shfl(lrun[mf], g4*4 + i, 64);
      float rl = 1.f/lt;
      u16* orow = O + ((size_t)(b*256 + w*64 + mf*16 + g4*4 + i))*384 + h*64;
#pragma unroll
      for(int df=0; df<4; ++df)
        orow[df*16 + l16] = f2bf(o[mf][df][i]*rl);
    }
}

// ================= Newton-Schulz: ONE cooperative kernel (48 blocks x 384 thr) =================
// Same per-iteration math/structure as the proven nsit_k chain; grid.sync between iterations
// replaces 18 kernel launches. 1 block/CU -> co-residency trivially satisfied.
static __device__ __forceinline__ void ns_mm(
    const u16* __restrict__ Agh, const u16* __restrict__ Agl,
    u16* AhL, u16* AlL, const u16* BThL, const u16* BTlL,
    int tid, f32x4 acc[4])
{
  const int w = tid>>6, lane = tid&63, g4 = lane>>4, l16 = lane&15;
  const int o0 = (tid>>1)*24 + (tid&1)*8;
  const int o1 = o0 + 4608;
  const s16x8 z8 = {0,0,0,0,0,0,0,0};
  f32x4 fz = {0.f,0.f,0.f,0.f};
#pragma unroll
  for(int i=0;i<4;i++) acc[i]=fz;
  {
    uint4 h0 = *(const uint4*)(Agh + tid*8);
    uint4 h1 = *(const uint4*)(Agh + (384+tid)*8);
    uint4 l0 = *(const uint4*)(Agl + tid*8);
    uint4 l1 = *(const uint4*)(Agl + (384+tid)*8);
    *(uint4*)&AhL[o0] = h0; *(uint4*)&AhL[o1] = h1;
    *(uint4*)&AlL[o0] = l0; *(uint4*)&AlL[o1] = l1;
  }
  __syncthreads();
  for(int c=0;c<24;c++){
    uint4 nh0, nh1, nl0, nl1;
    if(c<23){
      const u16* ph = Agh + (c+1)*6144;
      const u16* pl = Agl + (c+1)*6144;
      nh0 = *(const uint4*)(ph + tid*8);
      nh1 = *(const uint4*)(ph + (384+tid)*8);
      nl0 = *(const uint4*)(pl + tid*8);
      nl1 = *(const uint4*)(pl + (384+tid)*8);
    }
    s16x8 bh = z8, bl = z8;
    if(g4<2){
      bh = *(const s16x8*)&BThL[l16*392 + c*16 + g4*8];
      bl = *(const s16x8*)&BTlL[l16*392 + c*16 + g4*8];
    }
#pragma unroll
    for(int tt=0;tt<4;tt++){
      int rb = 64*w + 16*tt + l16;
      s16x8 ah = z8, al = z8;
      if(g4<2){
        ah = *(const s16x8*)&AhL[rb*24 + g4*8];
        al = *(const s16x8*)&AlL[rb*24 + g4*8];
      }
      acc[tt] = __builtin_amdgcn_mfma_f32_16x16x32_bf16(ah, bh, acc[tt], 0,0,0);
      acc[tt] = __builtin_amdgcn_mfma_f32_16x16x32_bf16(ah, bl, acc[tt], 0,0,0);
      acc[tt] = __builtin_amdgcn_mfma_f32_16x16x32_bf16(al, bh, acc[tt], 0,0,0);
    }
    __syncthreads();
    if(c<23){
      *(uint4*)&AhL[o0] = nh0; *(uint4*)&AhL[o1] = nh1;
      *(uint4*)&AlL[o0] = nl0; *(uint4*)&AlL[o1] = nl1;
      __syncthreads();
    }
  }
}

__global__ __launch_bounds__(384,1) void ns_all_k(const float* __restrict__ W0,
                                                  const float* __restrict__ W1,
                                                  float* __restrict__ part,
                                                  u16* __restrict__ XB,
                                                  u16* __restrict__ QT,
                                                  int niter, int nq)
{
  cg::grid_group grid = cg::this_grid();
  __shared__ __align__(16) u16 AhL[384*24];
  __shared__ __align__(16) u16 AlL[384*24];
  __shared__ __align__(16) u16 BTh[16*392];
  __shared__ __align__(16) u16 BTl[16*392];
  __shared__ float red[6];
  const int blk = blockIdx.x;
  const int z = blk/24, p = blk - z*24, cp0 = p*16;
  const int tid = threadIdx.x;
  const int w = tid>>6, lane = tid&63, g4 = lane>>4, l16 = lane&15;
  const float* W = z ? W1 : W0;

  // --- phase 1: Frobenius partial over this block's segment ---
  {
    float s = 0.f;
    const float* seg = W + p*6144;
    for(int i=tid;i<6144;i+=384){ float v=seg[i]; s+=v*v; }
#pragma unroll
    for(int off=32; off>0; off>>=1) s += __shfl_down(s, off, 64);
    if(lane==0) red[w]=s;
    __syncthreads();
    if(tid==0){
      float a = red[0]+red[1]+red[2]+red[3]+red[4]+red[5];
      part[blk]=a;
    }
  }
  grid.sync();
  // --- phase 2: combine (redundant, identical order per block) + init set 0 ---
  {
    float a=0.f;
#pragma unroll 4
    for(int i=0;i<24;i++) a += part[z*24+i];
    float inv = rsqrtf(a);
    u16* base = XB + (size_t)z*589824;
    u16* xh = base;            u16* xl = base + 147456;
    u16* th = base + 294912;   u16* tl = base + 442368;
    for(int idx=tid; idx<6144; idx+=384){
      int r = idx>>4, j = idx&15;
      float v = W[r*384 + cp0 + j]*inv;
      u16 hh = f2bf(v);
      xh[p*6144 + idx] = hh;
      xl[p*6144 + idx] = f2bf(v - bf2f(hh));
    }
    for(int idx=tid; idx<6144; idx+=384){
      int j = idx/384, r = idx - j*384;
      float v = W[(cp0+j)*384 + r]*inv;
      u16 hh = f2bf(v);
      th[p*6144 + r*16 + j] = hh;
      tl[p*6144 + r*16 + j] = f2bf(v - bf2f(hh));
    }
  }
  grid.sync();

  // --- phase 3: iterations (10 quintic + 5 cubic), 1 grid.sync per iteration ---
  for(int it=0; it<niter; ++it){
    const int rs = it&1;
    const u16* bin  = XB + (size_t)rs*1179648     + (size_t)z*589824;
    u16*       bout = XB + (size_t)(rs^1)*1179648 + (size_t)z*589824;
    const u16* Xh  = bin;            const u16* Xl  = bin + 147456;
    const u16* Th  = bin + 294912;   const u16* Tl  = bin + 442368;

    // stage BT' = transpose of XcA chunk p
    {
      const u16* sh = Xh + p*6144;
      const u16* sl = Xl + p*6144;
      for(int i=tid; i<768; i+=384){
        int k = i>>1, n0 = (i&1)*8;
        uint4 vh = *(const uint4*)(sh + i*8);
        uint4 vl = *(const uint4*)(sl + i*8);
#pragma unroll
        for(int j=0;j<8;j++){
          BTh[(n0+j)*392 + k] = ((u16*)&vh)[j];
          BTl[(n0+j)*392 + k] = ((u16*)&vl)[j];
        }
      }
    }
    __syncthreads();

    const bool quint = (it < nq);
    f32x4 acc[4], gsv[4];

    ns_mm(Th, Tl, AhL, AlL, BTh, BTl, tid, acc);
    if(quint){
#pragma unroll
      for(int tt=0;tt<4;tt++){
        gsv[tt] = acc[tt];
        int m0 = 64*w + 16*tt + g4*4;
        ushort4 h4, l4;
#pragma unroll
        for(int i=0;i<4;i++){
          float v = acc[tt][i];
          u16 hh = f2bf(v);
          ((u16*)&h4)[i]=hh; ((u16*)&l4)[i]=f2bf(v - bf2f(hh));
        }
        *(ushort4*)&BTh[l16*392 + m0] = h4;
        *(ushort4*)&BTl[l16*392 + m0] = l4;
      }
      __syncthreads();
      ns_mm(Xh, Xl, AhL, AlL, BTh, BTl, tid, acc);
#pragma unroll
      for(int tt=0;tt<4;tt++){
        int m0 = 64*w + 16*tt + g4*4;
        ushort4 h4, l4;
#pragma unroll
        for(int i=0;i<4;i++){
          float v = acc[tt][i];
          u16 hh = f2bf(v);
          ((u16*)&h4)[i]=hh; ((u16*)&l4)[i]=f2bf(v - bf2f(hh));
        }
        *(ushort4*)&BTh[l16*392 + m0] = h4;
        *(ushort4*)&BTl[l16*392 + m0] = l4;
      }
      __syncthreads();
      ns_mm(Th, Tl, AhL, AlL, BTh, BTl, tid, acc);
      __syncthreads();
#pragma unroll
      for(int tt=0;tt<4;tt++){
        int m0 = 64*w + 16*tt + g4*4;
        ushort4 h4, l4;
#pragma unroll
        for(int i=0;i<4;i++){
          float v = fmaf(2.0315f, acc[tt][i], -4.7750f*(gsv[tt][i]))
                  + ((m0+i)==(cp0+l16) ? 3.4445f : 0.f);
          u16 hh = f2bf(v);
          ((u16*)&h4)[i]=hh; ((u16*)&l4)[i]=f2bf(v - bf2f(hh));
        }
        *(ushort4*)&BTh[l16*392 + m0] = h4;
        *(ushort4*)&BTl[l16*392 + m0] = l4;
      }
      __syncthreads();
    } else {
#pragma unroll
      for(int tt=0;tt<4;tt++){
        int m0 = 64*w + 16*tt + g4*4;
        ushort4 h4, l4;
#pragma unroll
        for(int i=0;i<4;i++){
          float v = -0.5f*acc[tt][i] + ((m0+i)==(cp0+l16) ? 1.5f : 0.f);
          u16 hh = f2bf(v);
          ((u16*)&h4)[i]=hh; ((u16*)&l4)[i]=f2bf(v - bf2f(hh));
        }
        *(ushort4*)&BTh[l16*392 + m0] = h4;
        *(ushort4*)&BTl[l16*392 + m0] = l4;
      }
      __syncthreads();
    }
    ns_mm(Xh, Xl, AhL, AlL, BTh, BTl, tid, acc);

    if(it == niter-1){
      u16* q = QT + (size_t)z*147456 + (size_t)(cp0+l16)*384;
#pragma unroll
      for(int tt=0;tt<4;tt++){
        int m0 = 64*w + 16*tt + g4*4;
        ushort4 h4;
#pragma unroll
        for(int i=0;i<4;i++) ((u16*)&h4)[i] = f2bf(acc[tt][i]);
        *(ushort4*)&q[m0] = h4;
      }
    } else {
      u16* oXh = bout + p*6144;            u16* oXl = bout + 147456 + p*6144;
      u16* oTh = bout + 294912;            u16* oTl = bout + 442368;
#pragma unroll
      for(int tt=0;tt<4;tt++){
        int m0 = 64*w + 16*tt + g4*4;
        ushort4 h4, l4;
#pragma unroll
        for(int i=0;i<4;i++){
          float v = acc[tt][i];
          u16 hh = f2bf(v);
          ((u16*)&h4)[i]=hh; ((u16*)&l4)[i]=f2bf(v - bf2f(hh));
          oXh[(m0+i)*16 + l16] = hh;
          oXl[(m0+i)*16 + l16] = ((u16*)&l4)[i];
        }
        size_t to = (size_t)(4*w+tt)*6144 + (size_t)(cp0+l16)*16 + g4*4;
        *(ushort4*)&oTh[to] = h4;
        *(ushort4*)&oTl[to] = l4;
      }
      grid.sync();
    }
  }
}

// ---------------- host-side orchestration ----------------
extern "C" void kernel_launch(void* const* d_in, const int* in_sizes, int n_in,
                              void* d_out, int out_size, void* d_ws, size_t ws_size,
                              hipStream_t stream)
{
  const float* x      = (const float*)d_in[0];
  const float* Wq     = (const float*)d_in[1];
  const float* Wk     = (const float*)d_in[2];
  const float* Wv     = (const float*)d_in[3];
  const float* Wp     = (const float*)d_in[4];
  const float* bp     = (const float*)d_in[5];
  const float* scale1 = (const float*)d_in[6];
  const float* scale2 = (const float*)d_in[7];
  const float* W1     = (const float*)d_in[8];
  const float* b1     = (const float*)d_in[9];
  const float* W2     = (const float*)d_in[10];
  const float* b2     = (const float*)d_in[11];
  const float* Wo_in  = (const float*)d_in[12];
  const float* Wo_out = (const float*)d_in[13];

  // ---- workspace layout ----
  char* ws = (char*)d_ws;
  u16* XB   = (u16*)(ws + 0);                 // NS X buffers (4.7 MB)
  u16* Wqkv = (u16*)(ws + 4719104L);          // [h][{q,k,v}][64][384] bf16
  u16* WpT  = (u16*)(ws + 5603840L);          // [384][384]
  u16* W1T  = (u16*)(ws + 5898752L);          // [307][384]
  u16* W2T  = (u16*)(ws + 6134528L);          // [384][320] (k-padded with zeros)
  u16* QT   = (u16*)(ws + 6380288L);          // orth(Wo_in)^T, orth(Wo_out)^T bf16
  float* part = (float*)(ws + 6970112L);      // 48 floats
  u16* h1b  = (u16*)(ws + 8388608L);          // S0: h1 -> h6                (48 MB)
  u16* qkvb = (u16*)(ws + 58720256L);         // S1-S3: qkv packed -> h2/h3/h4 (144 MB)
  u16* atb  = (u16*)(ws + 209715200L);        // S4: attn_cat [65536][384] -> h5 [65536][320]
  u16* h2b = qkvb;
  u16* h3b = qkvb + 25165824L;
  u16* h4b = qkvb + 50331648L;
  u16* h5b = atb;
  u16* h6b = h1b;

  // --- weight transpose+cast ---
  tcast_k<<<dim3(12, 2,6),256,0,stream>>>(Wq,24576L, Wqkv,        73728L, 384, 64,384);
  tcast_k<<<dim3(12, 2,6),256,0,stream>>>(Wk,24576L, Wqkv+24576L, 73728L, 384, 64,384);
  tcast_k<<<dim3(12, 2,6),256,0,stream>>>(Wv,24576L, Wqkv+49152L, 73728L, 384, 64,384);
  tcast_k<<<dim3(12,12,1),256,0,stream>>>(Wp,0L,     WpT,0L,     384,384,384);
  tcast_k<<<dim3(12,10,1),256,0,stream>>>(W1,0L,     W1T,0L,     384,307,384);
  tcast_k<<<dim3(10,12,1),256,0,stream>>>(W2,0L,     W2T,0L,     307,384,320);

  // --- orth: one cooperative NS kernel (10 quintic + 5 cubic) ---
  {
    const float* a0 = Wo_in; const float* a1 = Wo_out;
    float* pp = part; u16* px = XB; u16* pq = QT;
    int ni = 15, nq = 10;
    void* nsargs[] = { (void*)&a0, (void*)&a1, (void*)&pp, (void*)&px,
                       (void*)&pq, (void*)&ni, (void*)&nq };
    hipLaunchCooperativeKernel((const void*)&ns_all_k, dim3(48), dim3(384),
                               nsargs, 0u, stream);
  }

  // --- main path: bf16 MFMA, BN=64 tiles, 4 blocks/CU, gload_lds staging ---
  rms_k<float,u16><<<16384,256,0,stream>>>(x, scale1, h1b);
  // QKV: N=1152 in 18 n-tiles, XCD-co-located; scatter to [b][h,j][t][64]
  mgemm2_k<2,u16,float><<<9216,256,0,stream>>>(
      h1b,384,  Wqkv,384,
      qkvb, 294912L,64,16384,
      (const float*)nullptr, nullptr,
      1152,1152,384, 0.f,0, 18);
  mattn_k<<<1536,256,0,stream>>>(qkvb, atb);
  // h2 = attn@Wp + bp + h1
  mgemm2_k<2,u16,u16><<<3072,256,0,stream>>>(
      atb,384,  WpT,384,
      h2b, 98304L,384,64,
      h1b, bp,
      384,384,384, 1.f,0, 6);
  rms_k<u16,u16><<<16384,256,0,stream>>>(h2b, scale2, h3b);
  // h4 = h3 @ orth(Wo_in)
  mgemm2_k<2,u16,float><<<3072,256,0,stream>>>(
      h3b,384,  QT,384,
      h4b, 98304L,384,64,
      (const float*)nullptr, nullptr,
      384,384,384, 0.f,0, 6);
  // h5 = relu(h4@W1 + b1), N=307 stored ld 320, cols 307..319 zeroed
  mgemm2_k<2,u16,float><<<2560,256,0,stream>>>(
      h4b,384,  W1T,384,
      h5b, 81920L,320,64,
      (const float*)nullptr, b1,
      307,320,384, 0.f,1, 5);
  // h6 = h5@W2 + b2  (K padded to 320)
  mgemm2_k<2,u16,float><<<3072,256,0,stream>>>(
      h5b,320,  W2T,320,
      h6b, 98304L,384,64,
      (const float*)nullptr, b2,
      384,384,320, 0.f,0, 6);
  // out = h6 @ orth(Wo_out) + h6 -> fp32 d_out
  mgemm2_k<2,float,u16><<<3072,256,0,stream>>>(
      h6b,384,  QT+147456,384,
      (float*)d_out, 98304L,384,64,
      h6b, nullptr,
      384,384,384, 1.f,0, 6);

  (void)in_sizes; (void)n_in; (void)ws_size; (void)out_size;
}